// Round 1
// baseline (2075.122 us; speedup 1.0000x reference)
//
#include <hip/hip_runtime.h>
#include <math.h>

#define DD 128

__device__ inline float wave_sum(float v){
#pragma unroll
  for (int m = 32; m >= 1; m >>= 1) v += __shfl_xor(v, m, 64);
  return v;
}
__device__ inline float wave_max(float v){
#pragma unroll
  for (int m = 32; m >= 1; m >>= 1) v = fmaxf(v, __shfl_xor(v, m, 64));
  return v;
}

// ---- setup kernels -------------------------------------------------------

__global__ void k_edge_offsets(const int* __restrict__ edges, int nnz, int E,
                               int* __restrict__ eo){
  int e = blockIdx.x * blockDim.x + threadIdx.x;
  if (e > E) return;
  int lo = 0, hi = nnz;                // first k with edges[k] >= e
  while (lo < hi){ int mid = (lo + hi) >> 1; if (edges[mid] < e) lo = mid + 1; else hi = mid; }
  eo[e] = lo;
}

__global__ void k_hist(const int* __restrict__ nodes, int nnz, int* __restrict__ dV){
  int k = blockIdx.x * blockDim.x + threadIdx.x;
  if (k < nnz) atomicAdd(&dV[nodes[k]], 1);
}

__global__ __launch_bounds__(1024) void k_scan(const int* __restrict__ dV, int N, int nnz,
                       int* __restrict__ no, int* __restrict__ nfill, float* __restrict__ degV){
  __shared__ int part[1024];
  int t = threadIdx.x;
  int chunk = (N + 1023) / 1024;
  int s0 = t * chunk, s1 = min(s0 + chunk, N);
  int sum = 0;
  for (int n = s0; n < s1; n++) sum += dV[n];
  part[t] = sum; __syncthreads();
  for (int off = 1; off < 1024; off <<= 1){
    int add = (t >= off) ? part[t - off] : 0;
    __syncthreads();
    part[t] += add;
    __syncthreads();
  }
  int run = part[t] - sum;            // exclusive prefix
  for (int n = s0; n < s1; n++){
    int d = dV[n];
    no[n] = run; nfill[n] = run;
    degV[n] = d > 0 ? 1.0f / sqrtf((float)d) : 1.0f;
    run += d;
  }
  if (t == 1023) no[N] = nnz;
}

__global__ void k_perm(const int* __restrict__ nodes, int nnz,
                       int* __restrict__ nfill, int* __restrict__ perm){
  int k = blockIdx.x * blockDim.x + threadIdx.x;
  if (k < nnz){ int pos = atomicAdd(&nfill[nodes[k]], 1); perm[pos] = k; }
}

__global__ void k_edge_deg(const int* __restrict__ nodes, const int* __restrict__ eo, int E,
                           const int* __restrict__ dV, float* __restrict__ degE){
  int e = blockIdx.x * blockDim.x + threadIdx.x;
  if (e >= E) return;
  int b = eo[e], en = eo[e + 1];
  float s = 0.f;
  for (int k = b; k < en; k++) s += (float)dV[nodes[k]];
  float cnt = (float)(en - b);
  float dE = s / fmaxf(cnt, 1.0f);
  degE[e] = dE > 0.f ? 1.0f / sqrtf(dE) : 1.0f;
}

// ---- per-layer kernels ---------------------------------------------------

// outA[r] = rows[r,:]·va ; outB[r] = rows[r,:]·vb   (wave per row)
__global__ __launch_bounds__(256) void k_scores(const float* __restrict__ rows, int nrows,
                        const float* __restrict__ va, const float* __restrict__ vb,
                        float* __restrict__ outA, float* __restrict__ outB){
  int wave = threadIdx.x >> 6, lane = threadIdx.x & 63;
  int r = blockIdx.x * 4 + wave;
  if (r >= nrows) return;
  const float2* rp = (const float2*)(rows + (size_t)r * DD);
  float2 x = rp[lane];
  float2 a = ((const float2*)va)[lane];
  float2 b = ((const float2*)vb)[lane];
  float s1 = x.x * a.x + x.y * a.y;
  float s2 = x.x * b.x + x.y * b.y;
  s1 = wave_sum(s1); s2 = wave_sum(s2);
  if (lane == 0){ outA[r] = s1; outB[r] = s2; }
}

// softmax over contiguous (sorted) edge segments; wave per edge
__global__ __launch_bounds__(256) void k_softmax_v2e(
    const int* __restrict__ nodes, const int* __restrict__ eo,
    const float* __restrict__ sx1, const float* __restrict__ se1,
    const float* __restrict__ dist, const float* __restrict__ deg,
    const float* __restrict__ ab, const float* __restrict__ wdw, const float* __restrict__ wdb,
    const float* __restrict__ wgw, const float* __restrict__ wgb, int li,
    int E, float* __restrict__ a_out){
  int wave = threadIdx.x >> 6, lane = threadIdx.x & 63;
  int e = blockIdx.x * 4 + wave;
  if (e >= E) return;
  int b = eo[e], en = eo[e + 1];
  if (b >= en) return;
  float base = se1[e] + ab[li] + wdb[li] + wgb[li];
  float wd = wdw[li], wg = wgw[li];
  float m = -INFINITY;
  for (int k = b + lane; k < en; k += 64){
    float s = sx1[nodes[k]] + base + dist[k] * wd + deg[k] * wg;
    a_out[k] = s;
    m = fmaxf(m, s);
  }
  m = wave_max(m);
  float sum = 0.f;
  for (int k = b + lane; k < en; k += 64){
    float ex = expf(a_out[k] - m);
    a_out[k] = ex; sum += ex;
  }
  sum = wave_sum(sum);
  for (int k = b + lane; k < en; k += 64) a_out[k] = a_out[k] / sum;
}

// softmax over node segments via CSR perm; thread per node
__global__ void k_softmax_e2v(const int* __restrict__ edges, const int* __restrict__ no,
    const int* __restrict__ perm,
    const float* __restrict__ se2, const float* __restrict__ sx2,
    const float* __restrict__ dist, const float* __restrict__ deg,
    const float* __restrict__ ab, const float* __restrict__ wdw, const float* __restrict__ wdb,
    const float* __restrict__ wgw, const float* __restrict__ wgb, int li,
    int N, float* __restrict__ a_out){
  int n = blockIdx.x * blockDim.x + threadIdx.x;
  if (n >= N) return;
  int b = no[n], en = no[n + 1];
  if (b >= en) return;
  float base = sx2[n] + ab[li] + wdb[li] + wgb[li];
  float wd = wdw[li], wg = wgw[li];
  float m = -INFINITY;
  for (int j = b; j < en; j++){ int k = perm[j];
    float s = se2[edges[k]] + base + dist[k] * wd + deg[k] * wg;
    a_out[k] = s; m = fmaxf(m, s); }
  float sum = 0.f;
  for (int j = b; j < en; j++){ int k = perm[j];
    float ex = expf(a_out[k] - m); a_out[k] = ex; sum += ex; }
  for (int j = b; j < en; j++){ int k = perm[j]; a_out[k] /= sum; }
}

// pass1: Xe1[e,:] = degE[e] * sum_k a_v2e[k]*x[nodes[k],:]   (wave per edge)
__global__ __launch_bounds__(256) void k_agg1(const int* __restrict__ nodes, const int* __restrict__ eo,
    const float* __restrict__ x, const float* __restrict__ a_v2e, const float* __restrict__ degE,
    int E, float* __restrict__ Xe1){
  int wave = threadIdx.x >> 6, lane = threadIdx.x & 63;
  int e = blockIdx.x * 4 + wave;
  if (e >= E) return;
  int b = eo[e], en = eo[e + 1];
  float2 acc = make_float2(0.f, 0.f);
  for (int k = b; k < en; k++){
    int n = nodes[k];
    float w = a_v2e[k];
    float2 v = *((const float2*)(x + (size_t)n * DD) + lane);
    acc.x += w * v.x; acc.y += w * v.y;
  }
  float dE = degE[e];
  *((float2*)(Xe1 + (size_t)e * DD) + lane) = make_float2(acc.x * dE, acc.y * dE);
}

// pass2: per node: Xv1 += a*Xe1[edge], Xv2 += a*ecur[edge]; write Xv2 and
// xi = 0.45*(Xv1+Xv2) + 0.1*x0    (wave per node)
__global__ __launch_bounds__(256) void k_agg2(const int* __restrict__ edges, const int* __restrict__ no,
    const int* __restrict__ perm,
    const float* __restrict__ Xe1, const float* __restrict__ ecur, const float* __restrict__ a_e2v,
    const float* __restrict__ degV, const float* __restrict__ x0,
    int N, float* __restrict__ Xv2, float* __restrict__ xi){
  int wave = threadIdx.x >> 6, lane = threadIdx.x & 63;
  int n = blockIdx.x * 4 + wave;
  if (n >= N) return;
  int b = no[n], en = no[n + 1];
  float2 a1 = make_float2(0.f, 0.f), a2 = make_float2(0.f, 0.f);
  for (int j = b; j < en; j++){
    int k = perm[j];
    int e = edges[k];
    float w = a_e2v[k];
    float2 v1 = *((const float2*)(Xe1 + (size_t)e * DD) + lane);
    float2 v2 = *((const float2*)(ecur + (size_t)e * DD) + lane);
    a1.x += w * v1.x; a1.y += w * v1.y;
    a2.x += w * v2.x; a2.y += w * v2.y;
  }
  float dv = degV[n];
  float2 xv1 = make_float2(a1.x * dv, a1.y * dv);
  float2 xv2 = make_float2(a2.x * dv, a2.y * dv);
  *((float2*)(Xv2 + (size_t)n * DD) + lane) = xv2;
  float2 x0v = *((const float2*)(x0 + (size_t)n * DD) + lane);
  float2 o = make_float2(0.45f * (xv1.x + xv2.x) + 0.1f * x0v.x,
                         0.45f * (xv1.y + xv2.y) + 0.1f * x0v.y);
  *((float2*)(xi + (size_t)n * DD) + lane) = o;
}

// pass3: per edge: Xe2 = degE*sum a_v2e*Xv2[node]; ei = 0.45*(Xe1+Xe2)+0.1*e0
__global__ __launch_bounds__(256) void k_agg3(const int* __restrict__ nodes, const int* __restrict__ eo,
    const float* __restrict__ Xv2, const float* __restrict__ a_v2e, const float* __restrict__ degE,
    const float* __restrict__ Xe1, const float* __restrict__ e0,
    int E, float* __restrict__ ei){
  int wave = threadIdx.x >> 6, lane = threadIdx.x & 63;
  int e = blockIdx.x * 4 + wave;
  if (e >= E) return;
  int b = eo[e], en = eo[e + 1];
  float2 acc = make_float2(0.f, 0.f);
  for (int k = b; k < en; k++){
    int n = nodes[k];
    float w = a_v2e[k];
    float2 v = *((const float2*)(Xv2 + (size_t)n * DD) + lane);
    acc.x += w * v.x; acc.y += w * v.y;
  }
  float dE = degE[e];
  float2 xe1 = *((const float2*)(Xe1 + (size_t)e * DD) + lane);
  float2 e0v = *((const float2*)(e0 + (size_t)e * DD) + lane);
  float2 o = make_float2(0.45f * (xe1.x + acc.x * dE) + 0.1f * e0v.x,
                         0.45f * (xe1.y + acc.y * dE) + 0.1f * e0v.y);
  *((float2*)(ei + (size_t)e * DD) + lane) = o;
}

// GEMM: out[r,c] = epilogue( sum_k A[r,k] * W[k,c] )
// mode 0: relu(acc + bias[c]);  mode 1: (1-beta)*A[r,c] + beta*acc (+relu)
// 64x64 tile, BK=32, 256 threads, 4x4 per thread
__global__ __launch_bounds__(256) void k_gemm(const float* __restrict__ A, const float* __restrict__ W,
    const float* __restrict__ bias, float* __restrict__ out, int nrows,
    float beta, int mode, int do_relu){
  __shared__ float As[32][68];   // As[k][r], padded
  __shared__ float Bs[32][64];   // Bs[k][c]
  int row0 = blockIdx.x * 64, col0 = blockIdx.y * 64;
  int tid = threadIdx.x;
  int tc = (tid & 15) * 4, tr = (tid >> 4) * 4;
  float acc[4][4] = {};
  for (int kt = 0; kt < 4; kt++){
#pragma unroll
    for (int i = 0; i < 2; i++){
      int f4 = tid + i * 256; int flat = f4 * 4;
      int r = flat >> 5, k = flat & 31;
      int gr = row0 + r;
      float4 v = make_float4(0.f, 0.f, 0.f, 0.f);
      if (gr < nrows) v = *(const float4*)(A + (size_t)gr * 128 + kt * 32 + k);
      As[k][r] = v.x; As[k + 1][r] = v.y; As[k + 2][r] = v.z; As[k + 3][r] = v.w;
    }
#pragma unroll
    for (int i = 0; i < 2; i++){
      int f4 = tid + i * 256; int flat = f4 * 4;
      int k = flat >> 6, c = flat & 63;
      *(float4*)&Bs[k][c] = *(const float4*)(W + (size_t)(kt * 32 + k) * 128 + col0 + c);
    }
    __syncthreads();
#pragma unroll 8
    for (int k = 0; k < 32; k++){
      float4 a = *(const float4*)&As[k][tr];
      float4 b = *(const float4*)&Bs[k][tc];
      float av[4] = {a.x, a.y, a.z, a.w};
      float bv[4] = {b.x, b.y, b.z, b.w};
#pragma unroll
      for (int ii = 0; ii < 4; ii++)
#pragma unroll
        for (int j = 0; j < 4; j++) acc[ii][j] += av[ii] * bv[j];
    }
    __syncthreads();
  }
#pragma unroll
  for (int ii = 0; ii < 4; ii++){
    int gr = row0 + tr + ii;
    if (gr >= nrows) continue;
    float ov[4];
    if (mode == 0){
#pragma unroll
      for (int j = 0; j < 4; j++){
        float v = acc[ii][j] + bias[col0 + tc + j];
        ov[j] = fmaxf(v, 0.f);
      }
    } else {
      float4 av4 = *(const float4*)(A + (size_t)gr * 128 + col0 + tc);
      float avv[4] = {av4.x, av4.y, av4.z, av4.w};
#pragma unroll
      for (int j = 0; j < 4; j++){
        float v = (1.0f - beta) * avv[j] + beta * acc[ii][j];
        if (do_relu) v = fmaxf(v, 0.f);
        ov[j] = v;
      }
    }
    *(float4*)(out + (size_t)gr * 128 + col0 + tc) = make_float4(ov[0], ov[1], ov[2], ov[3]);
  }
}

// ---- host ----------------------------------------------------------------

extern "C" void kernel_launch(void* const* d_in, const int* in_sizes, int n_in,
                              void* d_out, int out_size, void* d_ws, size_t ws_size,
                              hipStream_t stream) {
  const float* x_in     = (const float*)d_in[0];
  const float* e_in     = (const float*)d_in[1];
  const int*   hei      = (const int*)d_in[2];
  const float* dist_v2e = (const float*)d_in[3];
  const float* deg_v2e  = (const float*)d_in[4];
  const float* dist_e2v = (const float*)d_in[5];
  const float* deg_e2v  = (const float*)d_in[6];
  const float* W0       = (const float*)d_in[7];
  const float* b0       = (const float*)d_in[8];
  const float* Wn       = (const float*)d_in[9];
  const float* We       = (const float*)d_in[10];
  const float* attn_w   = (const float*)d_in[11];
  const float* attn_b   = (const float*)d_in[12];
  const float* wd_w     = (const float*)d_in[13];
  const float* wd_b     = (const float*)d_in[14];
  const float* wg_w     = (const float*)d_in[15];
  const float* wg_b     = (const float*)d_in[16];

  const int N   = in_sizes[0] / DD;
  const int E   = in_sizes[1] / DD;
  const int NNZ = in_sizes[2] / 2;
  const int* nodesArr = hei;
  const int* edgesArr = hei + NNZ;

  float* out_x = (float*)d_out;
  float* out_e = (float*)d_out + (size_t)N * DD;

  char* wsp = (char*)d_ws;
  auto alloc = [&](size_t bytes) -> void* {
    void* p = (void*)wsp;
    wsp += (bytes + 255) / 256 * 256;
    return p;
  };
  float* x0buf = (float*)alloc((size_t)N * DD * 4);
  float* xS1   = (float*)alloc((size_t)N * DD * 4);
  float* xS2   = (float*)alloc((size_t)N * DD * 4);
  float* eS1   = (float*)alloc((size_t)E * DD * 4);
  float* eS2   = (float*)alloc((size_t)E * DD * 4);
  float* sx1   = (float*)alloc((size_t)N * 4);
  float* sx2   = (float*)alloc((size_t)N * 4);
  float* se1   = (float*)alloc((size_t)E * 4);
  float* se2   = (float*)alloc((size_t)E * 4);
  float* a_v2e = (float*)alloc((size_t)NNZ * 4);
  float* a_e2v = (float*)alloc((size_t)NNZ * 4);
  float* degV  = (float*)alloc((size_t)N * 4);
  float* degE  = (float*)alloc((size_t)E * 4);
  int* dV_i  = (int*)alloc((size_t)N * 4);
  int* no_   = (int*)alloc((size_t)(N + 1) * 4);
  int* nfill = (int*)alloc((size_t)N * 4);
  int* perm  = (int*)alloc((size_t)NNZ * 4);
  int* eo    = (int*)alloc((size_t)(E + 1) * 4);

  // Xv2 / Xe1 live in the (poisoned-then-final-overwritten) d_out regions
  float* Xv2 = out_x;
  float* Xe1 = out_e;

  // ---- setup
  hipMemsetAsync(dV_i, 0, (size_t)N * 4, stream);
  k_edge_offsets<<<(E + 1 + 255) / 256, 256, 0, stream>>>(edgesArr, NNZ, E, eo);
  k_hist<<<(NNZ + 255) / 256, 256, 0, stream>>>(nodesArr, NNZ, dV_i);
  k_scan<<<1, 1024, 0, stream>>>(dV_i, N, NNZ, no_, nfill, degV);
  k_perm<<<(NNZ + 255) / 256, 256, 0, stream>>>(nodesArr, NNZ, nfill, perm);
  k_edge_deg<<<(E + 255) / 256, 256, 0, stream>>>(nodesArr, eo, E, dV_i, degE);

  // x0 = relu(x @ W0 + b0)
  dim3 g0((N + 63) / 64, 2);
  k_gemm<<<g0, 256, 0, stream>>>(x_in, W0, b0, x0buf, N, 0.f, 0, 1);

  const float* xcur = x0buf;
  const float* ecur = e_in;

  for (int i = 0; i < 4; i++){
    float beta = logf(0.5f / (float)(i + 1) + 1.0f);
    float* xi_t = (i == 0) ? xS1 : (float*)xcur;
    float* xnew = (i == 3) ? out_x : ((i == 0 || i == 2) ? xS2 : xS1);
    float* ei_t = (i == 0) ? eS1 : (float*)ecur;
    float* enew = (i == 3) ? out_e : ((i == 0 || i == 2) ? eS2 : eS1);

    const float* aw1 = attn_w + (size_t)i * 256;        // aw[i,:d]
    const float* aw2 = attn_w + (size_t)i * 256 + 128;  // aw[i,d:]

    // scores: sx1 = x@aw1, sx2 = x@aw2 ; se1 = e@aw2, se2 = e@aw1
    k_scores<<<(N + 3) / 4, 256, 0, stream>>>(xcur, N, aw1, aw2, sx1, sx2);
    k_scores<<<(E + 3) / 4, 256, 0, stream>>>(ecur, E, aw2, aw1, se1, se2);

    k_softmax_v2e<<<(E + 3) / 4, 256, 0, stream>>>(nodesArr, eo, sx1, se1,
        dist_v2e, deg_v2e, attn_b, wd_w, wd_b, wg_w, wg_b, i, E, a_v2e);
    k_softmax_e2v<<<(N + 255) / 256, 256, 0, stream>>>(edgesArr, no_, perm, se2, sx2,
        dist_e2v, deg_e2v, attn_b, wd_w, wd_b, wg_w, wg_b, i, N, a_e2v);

    k_agg1<<<(E + 3) / 4, 256, 0, stream>>>(nodesArr, eo, xcur, a_v2e, degE, E, Xe1);
    k_agg2<<<(N + 3) / 4, 256, 0, stream>>>(edgesArr, no_, perm, Xe1, ecur, a_e2v,
                                            degV, x0buf, N, Xv2, xi_t);
    k_agg3<<<(E + 3) / 4, 256, 0, stream>>>(nodesArr, eo, Xv2, a_v2e, degE, Xe1, e_in, E, ei_t);

    dim3 gx((N + 63) / 64, 2), ge((E + 63) / 64, 2);
    k_gemm<<<gx, 256, 0, stream>>>(xi_t, Wn + (size_t)i * DD * DD, nullptr, xnew, N, beta, 1, i < 3 ? 1 : 0);
    k_gemm<<<ge, 256, 0, stream>>>(ei_t, We + (size_t)i * DD * DD, nullptr, enew, E, beta, 1, i < 3 ? 1 : 0);

    xcur = xnew; ecur = enew;
  }
}

// Round 2
// 1814.765 us; speedup vs baseline: 1.1435x; 1.1435x over previous
//
#include <hip/hip_runtime.h>
#include <math.h>

#define DD 128
#define SCAN_BLOCKS 256

__device__ inline float wave_sum(float v){
#pragma unroll
  for (int m = 32; m >= 1; m >>= 1) v += __shfl_xor(v, m, 64);
  return v;
}
__device__ inline float wave_max(float v){
#pragma unroll
  for (int m = 32; m >= 1; m >>= 1) v = fmaxf(v, __shfl_xor(v, m, 64));
  return v;
}
__device__ inline int wave_sum_i(int v){
#pragma unroll
  for (int m = 32; m >= 1; m >>= 1) v += __shfl_xor(v, m, 64);
  return v;
}

// ---- setup kernels -------------------------------------------------------

__global__ void k_edge_offsets(const int* __restrict__ edges, int nnz, int E,
                               int* __restrict__ eo){
  int e = blockIdx.x * blockDim.x + threadIdx.x;
  if (e > E) return;
  int lo = 0, hi = nnz;                // first k with edges[k] >= e
  while (lo < hi){ int mid = (lo + hi) >> 1; if (edges[mid] < e) lo = mid + 1; else hi = mid; }
  eo[e] = lo;
}

__global__ void k_hist(const int* __restrict__ nodes, int nnz, int* __restrict__ dV){
  int k = blockIdx.x * blockDim.x + threadIdx.x;
  if (k < nnz) atomicAdd(&dV[nodes[k]], 1);
}

// Phase A: per-block partial sums of dV (coalesced grid over chunk)
__global__ __launch_bounds__(256) void k_scan_partial(const int* __restrict__ dV, int N,
                                                      int* __restrict__ part){
  int b = blockIdx.x, t = threadIdx.x;
  int chunk = (N + SCAN_BLOCKS - 1) / SCAN_BLOCKS;
  int s0 = b * chunk, s1 = min(s0 + chunk, N);
  int sum = 0;
  for (int n = s0 + t; n < s1; n += 256) sum += dV[n];
  sum = wave_sum_i(sum);
  __shared__ int wred[4];
  int lane = t & 63, wid = t >> 6;
  if (lane == 0) wred[wid] = sum;
  __syncthreads();
  if (t == 0) part[b] = wred[0] + wred[1] + wred[2] + wred[3];
}

// Phase B: exclusive scan of the SCAN_BLOCKS partial sums (single block)
__global__ __launch_bounds__(SCAN_BLOCKS) void k_scan_blocksums(int* __restrict__ part){
  __shared__ int sh[SCAN_BLOCKS];
  int t = threadIdx.x;
  int v = part[t];
  sh[t] = v; __syncthreads();
  for (int off = 1; off < SCAN_BLOCKS; off <<= 1){
    int add = (t >= off) ? sh[t - off] : 0;
    __syncthreads();
    sh[t] += add;
    __syncthreads();
  }
  part[t] = sh[t] - v;   // exclusive
}

// Phase C: apply — in-block scan of each 256-tile, write no/nfill/degV
__global__ __launch_bounds__(256) void k_scan_apply(const int* __restrict__ dV, int N, int nnz,
    const int* __restrict__ partScan, int* __restrict__ no, int* __restrict__ nfill,
    float* __restrict__ degV){
  int b = blockIdx.x, t = threadIdx.x;
  int chunk = (N + SCAN_BLOCKS - 1) / SCAN_BLOCKS;
  int s0 = b * chunk, s1 = min(s0 + chunk, N);
  int lane = t & 63, wid = t >> 6;
  __shared__ int wtot[4];
  __shared__ int s_run;
  if (t == 0) s_run = partScan[b];
  __syncthreads();
  for (int base = s0; base < s1; base += 256){
    int n = base + t;
    int d = (n < s1) ? dV[n] : 0;
    int v = d;
#pragma unroll
    for (int off = 1; off < 64; off <<= 1){
      int o = __shfl_up(v, off, 64);
      if (lane >= off) v += o;
    }
    if (lane == 63) wtot[wid] = v;
    __syncthreads();
    int run0 = s_run;
    int woff = 0;
    for (int w = 0; w < wid; w++) woff += wtot[w];
    if (n < s1){
      int excl = run0 + woff + v - d;
      no[n] = excl; nfill[n] = excl;
      degV[n] = d > 0 ? 1.0f / sqrtf((float)d) : 1.0f;
    }
    int btot = wtot[0] + wtot[1] + wtot[2] + wtot[3];
    __syncthreads();
    if (t == 0) s_run = run0 + btot;
    __syncthreads();
  }
  if (b == 0 && t == 0) no[N] = nnz;
}

__global__ void k_perm(const int* __restrict__ nodes, int nnz,
                       int* __restrict__ nfill, int* __restrict__ perm){
  int k = blockIdx.x * blockDim.x + threadIdx.x;
  if (k < nnz){ int pos = atomicAdd(&nfill[nodes[k]], 1); perm[pos] = k; }
}

__global__ void k_edge_deg(const int* __restrict__ nodes, const int* __restrict__ eo, int E,
                           const int* __restrict__ dV, float* __restrict__ degE){
  int e = blockIdx.x * blockDim.x + threadIdx.x;
  if (e >= E) return;
  int b = eo[e], en = eo[e + 1];
  float s = 0.f;
  for (int k = b; k < en; k++) s += (float)dV[nodes[k]];
  float cnt = (float)(en - b);
  float dE = s / fmaxf(cnt, 1.0f);
  degE[e] = dE > 0.f ? 1.0f / sqrtf(dE) : 1.0f;
}

// ---- per-layer kernels ---------------------------------------------------

// outA[r] = rows[r,:]·va ; outB[r] = rows[r,:]·vb   (wave per row)
__global__ __launch_bounds__(256) void k_scores(const float* __restrict__ rows, int nrows,
                        const float* __restrict__ va, const float* __restrict__ vb,
                        float* __restrict__ outA, float* __restrict__ outB){
  int wave = threadIdx.x >> 6, lane = threadIdx.x & 63;
  int r = blockIdx.x * 4 + wave;
  if (r >= nrows) return;
  const float2* rp = (const float2*)(rows + (size_t)r * DD);
  float2 x = rp[lane];
  float2 a = ((const float2*)va)[lane];
  float2 b = ((const float2*)vb)[lane];
  float s1 = x.x * a.x + x.y * a.y;
  float s2 = x.x * b.x + x.y * b.y;
  s1 = wave_sum(s1); s2 = wave_sum(s2);
  if (lane == 0){ outA[r] = s1; outB[r] = s2; }
}

// softmax over contiguous (sorted) edge segments; wave per edge
__global__ __launch_bounds__(256) void k_softmax_v2e(
    const int* __restrict__ nodes, const int* __restrict__ eo,
    const float* __restrict__ sx1, const float* __restrict__ se1,
    const float* __restrict__ dist, const float* __restrict__ deg,
    const float* __restrict__ ab, const float* __restrict__ wdw, const float* __restrict__ wdb,
    const float* __restrict__ wgw, const float* __restrict__ wgb, int li,
    int E, float* __restrict__ a_out){
  int wave = threadIdx.x >> 6, lane = threadIdx.x & 63;
  int e = blockIdx.x * 4 + wave;
  if (e >= E) return;
  int b = eo[e], en = eo[e + 1];
  if (b >= en) return;
  float base = se1[e] + ab[li] + wdb[li] + wgb[li];
  float wd = wdw[li], wg = wgw[li];
  float m = -INFINITY;
  for (int k = b + lane; k < en; k += 64){
    float s = sx1[nodes[k]] + base + dist[k] * wd + deg[k] * wg;
    a_out[k] = s;
    m = fmaxf(m, s);
  }
  m = wave_max(m);
  float sum = 0.f;
  for (int k = b + lane; k < en; k += 64){
    float ex = expf(a_out[k] - m);
    a_out[k] = ex; sum += ex;
  }
  sum = wave_sum(sum);
  for (int k = b + lane; k < en; k += 64) a_out[k] = a_out[k] / sum;
}

// softmax over node segments via CSR perm; thread per node
__global__ void k_softmax_e2v(const int* __restrict__ edges, const int* __restrict__ no,
    const int* __restrict__ perm,
    const float* __restrict__ se2, const float* __restrict__ sx2,
    const float* __restrict__ dist, const float* __restrict__ deg,
    const float* __restrict__ ab, const float* __restrict__ wdw, const float* __restrict__ wdb,
    const float* __restrict__ wgw, const float* __restrict__ wgb, int li,
    int N, float* __restrict__ a_out){
  int n = blockIdx.x * blockDim.x + threadIdx.x;
  if (n >= N) return;
  int b = no[n], en = no[n + 1];
  if (b >= en) return;
  float base = sx2[n] + ab[li] + wdb[li] + wgb[li];
  float wd = wdw[li], wg = wgw[li];
  float m = -INFINITY;
  for (int j = b; j < en; j++){ int k = perm[j];
    float s = se2[edges[k]] + base + dist[k] * wd + deg[k] * wg;
    a_out[k] = s; m = fmaxf(m, s); }
  float sum = 0.f;
  for (int j = b; j < en; j++){ int k = perm[j];
    float ex = expf(a_out[k] - m); a_out[k] = ex; sum += ex; }
  for (int j = b; j < en; j++){ int k = perm[j]; a_out[k] /= sum; }
}

// pass1: Xe1[e,:] = degE[e] * sum_k a_v2e[k]*x[nodes[k],:]   (wave per edge)
__global__ __launch_bounds__(256) void k_agg1(const int* __restrict__ nodes, const int* __restrict__ eo,
    const float* __restrict__ x, const float* __restrict__ a_v2e, const float* __restrict__ degE,
    int E, float* __restrict__ Xe1){
  int wave = threadIdx.x >> 6, lane = threadIdx.x & 63;
  int e = blockIdx.x * 4 + wave;
  if (e >= E) return;
  int b = eo[e], en = eo[e + 1];
  float2 acc = make_float2(0.f, 0.f);
  for (int k = b; k < en; k++){
    int n = nodes[k];
    float w = a_v2e[k];
    float2 v = *((const float2*)(x + (size_t)n * DD) + lane);
    acc.x += w * v.x; acc.y += w * v.y;
  }
  float dE = degE[e];
  *((float2*)(Xe1 + (size_t)e * DD) + lane) = make_float2(acc.x * dE, acc.y * dE);
}

// pass2: per node: Xv1 += a*Xe1[edge], Xv2 += a*ecur[edge]; write Xv2 and
// xi = 0.45*(Xv1+Xv2) + 0.1*x0    (wave per node)
__global__ __launch_bounds__(256) void k_agg2(const int* __restrict__ edges, const int* __restrict__ no,
    const int* __restrict__ perm,
    const float* __restrict__ Xe1, const float* __restrict__ ecur, const float* __restrict__ a_e2v,
    const float* __restrict__ degV, const float* __restrict__ x0,
    int N, float* __restrict__ Xv2, float* __restrict__ xi){
  int wave = threadIdx.x >> 6, lane = threadIdx.x & 63;
  int n = blockIdx.x * 4 + wave;
  if (n >= N) return;
  int b = no[n], en = no[n + 1];
  float2 a1 = make_float2(0.f, 0.f), a2 = make_float2(0.f, 0.f);
  for (int j = b; j < en; j++){
    int k = perm[j];
    int e = edges[k];
    float w = a_e2v[k];
    float2 v1 = *((const float2*)(Xe1 + (size_t)e * DD) + lane);
    float2 v2 = *((const float2*)(ecur + (size_t)e * DD) + lane);
    a1.x += w * v1.x; a1.y += w * v1.y;
    a2.x += w * v2.x; a2.y += w * v2.y;
  }
  float dv = degV[n];
  float2 xv1 = make_float2(a1.x * dv, a1.y * dv);
  float2 xv2 = make_float2(a2.x * dv, a2.y * dv);
  *((float2*)(Xv2 + (size_t)n * DD) + lane) = xv2;
  float2 x0v = *((const float2*)(x0 + (size_t)n * DD) + lane);
  float2 o = make_float2(0.45f * (xv1.x + xv2.x) + 0.1f * x0v.x,
                         0.45f * (xv1.y + xv2.y) + 0.1f * x0v.y);
  *((float2*)(xi + (size_t)n * DD) + lane) = o;
}

// pass3: per edge: Xe2 = degE*sum a_v2e*Xv2[node]; ei = 0.45*(Xe1+Xe2)+0.1*e0
__global__ __launch_bounds__(256) void k_agg3(const int* __restrict__ nodes, const int* __restrict__ eo,
    const float* __restrict__ Xv2, const float* __restrict__ a_v2e, const float* __restrict__ degE,
    const float* __restrict__ Xe1, const float* __restrict__ e0,
    int E, float* __restrict__ ei){
  int wave = threadIdx.x >> 6, lane = threadIdx.x & 63;
  int e = blockIdx.x * 4 + wave;
  if (e >= E) return;
  int b = eo[e], en = eo[e + 1];
  float2 acc = make_float2(0.f, 0.f);
  for (int k = b; k < en; k++){
    int n = nodes[k];
    float w = a_v2e[k];
    float2 v = *((const float2*)(Xv2 + (size_t)n * DD) + lane);
    acc.x += w * v.x; acc.y += w * v.y;
  }
  float dE = degE[e];
  float2 xe1 = *((const float2*)(Xe1 + (size_t)e * DD) + lane);
  float2 e0v = *((const float2*)(e0 + (size_t)e * DD) + lane);
  float2 o = make_float2(0.45f * (xe1.x + acc.x * dE) + 0.1f * e0v.x,
                         0.45f * (xe1.y + acc.y * dE) + 0.1f * e0v.y);
  *((float2*)(ei + (size_t)e * DD) + lane) = o;
}

// GEMM: out[r,c] = epilogue( sum_k A[r,k] * W[k,c] )
// mode 0: relu(acc + bias[c]);  mode 1: (1-beta)*A[r,c] + beta*acc (+relu)
// 64x64 tile, BK=32, 256 threads, 4x4 per thread
__global__ __launch_bounds__(256) void k_gemm(const float* __restrict__ A, const float* __restrict__ W,
    const float* __restrict__ bias, float* __restrict__ out, int nrows,
    float beta, int mode, int do_relu){
  __shared__ float As[32][68];   // As[k][r], padded
  __shared__ float Bs[32][64];   // Bs[k][c]
  int row0 = blockIdx.x * 64, col0 = blockIdx.y * 64;
  int tid = threadIdx.x;
  int tc = (tid & 15) * 4, tr = (tid >> 4) * 4;
  float acc[4][4] = {};
  for (int kt = 0; kt < 4; kt++){
#pragma unroll
    for (int i = 0; i < 2; i++){
      int f4 = tid + i * 256; int flat = f4 * 4;
      int r = flat >> 5, k = flat & 31;
      int gr = row0 + r;
      float4 v = make_float4(0.f, 0.f, 0.f, 0.f);
      if (gr < nrows) v = *(const float4*)(A + (size_t)gr * 128 + kt * 32 + k);
      As[k][r] = v.x; As[k + 1][r] = v.y; As[k + 2][r] = v.z; As[k + 3][r] = v.w;
    }
#pragma unroll
    for (int i = 0; i < 2; i++){
      int f4 = tid + i * 256; int flat = f4 * 4;
      int k = flat >> 6, c = flat & 63;
      *(float4*)&Bs[k][c] = *(const float4*)(W + (size_t)(kt * 32 + k) * 128 + col0 + c);
    }
    __syncthreads();
#pragma unroll 8
    for (int k = 0; k < 32; k++){
      float4 a = *(const float4*)&As[k][tr];
      float4 b = *(const float4*)&Bs[k][tc];
      float av[4] = {a.x, a.y, a.z, a.w};
      float bv[4] = {b.x, b.y, b.z, b.w};
#pragma unroll
      for (int ii = 0; ii < 4; ii++)
#pragma unroll
        for (int j = 0; j < 4; j++) acc[ii][j] += av[ii] * bv[j];
    }
    __syncthreads();
  }
#pragma unroll
  for (int ii = 0; ii < 4; ii++){
    int gr = row0 + tr + ii;
    if (gr >= nrows) continue;
    float ov[4];
    if (mode == 0){
#pragma unroll
      for (int j = 0; j < 4; j++){
        float v = acc[ii][j] + bias[col0 + tc + j];
        ov[j] = fmaxf(v, 0.f);
      }
    } else {
      float4 av4 = *(const float4*)(A + (size_t)gr * 128 + col0 + tc);
      float avv[4] = {av4.x, av4.y, av4.z, av4.w};
#pragma unroll
      for (int j = 0; j < 4; j++){
        float v = (1.0f - beta) * avv[j] + beta * acc[ii][j];
        if (do_relu) v = fmaxf(v, 0.f);
        ov[j] = v;
      }
    }
    *(float4*)(out + (size_t)gr * 128 + col0 + tc) = make_float4(ov[0], ov[1], ov[2], ov[3]);
  }
}

// ---- host ----------------------------------------------------------------

extern "C" void kernel_launch(void* const* d_in, const int* in_sizes, int n_in,
                              void* d_out, int out_size, void* d_ws, size_t ws_size,
                              hipStream_t stream) {
  const float* x_in     = (const float*)d_in[0];
  const float* e_in     = (const float*)d_in[1];
  const int*   hei      = (const int*)d_in[2];
  const float* dist_v2e = (const float*)d_in[3];
  const float* deg_v2e  = (const float*)d_in[4];
  const float* dist_e2v = (const float*)d_in[5];
  const float* deg_e2v  = (const float*)d_in[6];
  const float* W0       = (const float*)d_in[7];
  const float* b0       = (const float*)d_in[8];
  const float* Wn       = (const float*)d_in[9];
  const float* We       = (const float*)d_in[10];
  const float* attn_w   = (const float*)d_in[11];
  const float* attn_b   = (const float*)d_in[12];
  const float* wd_w     = (const float*)d_in[13];
  const float* wd_b     = (const float*)d_in[14];
  const float* wg_w     = (const float*)d_in[15];
  const float* wg_b     = (const float*)d_in[16];

  const int N   = in_sizes[0] / DD;
  const int E   = in_sizes[1] / DD;
  const int NNZ = in_sizes[2] / 2;
  const int* nodesArr = hei;
  const int* edgesArr = hei + NNZ;

  float* out_x = (float*)d_out;
  float* out_e = (float*)d_out + (size_t)N * DD;

  char* wsp = (char*)d_ws;
  auto alloc = [&](size_t bytes) -> void* {
    void* p = (void*)wsp;
    wsp += (bytes + 255) / 256 * 256;
    return p;
  };
  float* x0buf = (float*)alloc((size_t)N * DD * 4);
  float* xS1   = (float*)alloc((size_t)N * DD * 4);
  float* xS2   = (float*)alloc((size_t)N * DD * 4);
  float* eS1   = (float*)alloc((size_t)E * DD * 4);
  float* eS2   = (float*)alloc((size_t)E * DD * 4);
  float* sx1   = (float*)alloc((size_t)N * 4);
  float* sx2   = (float*)alloc((size_t)N * 4);
  float* se1   = (float*)alloc((size_t)E * 4);
  float* se2   = (float*)alloc((size_t)E * 4);
  float* a_v2e = (float*)alloc((size_t)NNZ * 4);
  float* a_e2v = (float*)alloc((size_t)NNZ * 4);
  float* degV  = (float*)alloc((size_t)N * 4);
  float* degE  = (float*)alloc((size_t)E * 4);
  int* dV_i  = (int*)alloc((size_t)N * 4);
  int* no_   = (int*)alloc((size_t)(N + 1) * 4);
  int* nfill = (int*)alloc((size_t)N * 4);
  int* perm  = (int*)alloc((size_t)NNZ * 4);
  int* eo    = (int*)alloc((size_t)(E + 1) * 4);
  int* part  = (int*)alloc((size_t)SCAN_BLOCKS * 4);

  // Xv2 / Xe1 live in the (poisoned-then-final-overwritten) d_out regions
  float* Xv2 = out_x;
  float* Xe1 = out_e;

  // ---- setup
  hipMemsetAsync(dV_i, 0, (size_t)N * 4, stream);
  k_edge_offsets<<<(E + 1 + 255) / 256, 256, 0, stream>>>(edgesArr, NNZ, E, eo);
  k_hist<<<(NNZ + 255) / 256, 256, 0, stream>>>(nodesArr, NNZ, dV_i);
  k_scan_partial<<<SCAN_BLOCKS, 256, 0, stream>>>(dV_i, N, part);
  k_scan_blocksums<<<1, SCAN_BLOCKS, 0, stream>>>(part);
  k_scan_apply<<<SCAN_BLOCKS, 256, 0, stream>>>(dV_i, N, NNZ, part, no_, nfill, degV);
  k_perm<<<(NNZ + 255) / 256, 256, 0, stream>>>(nodesArr, NNZ, nfill, perm);
  k_edge_deg<<<(E + 255) / 256, 256, 0, stream>>>(nodesArr, eo, E, dV_i, degE);

  // x0 = relu(x @ W0 + b0)
  dim3 g0((N + 63) / 64, 2);
  k_gemm<<<g0, 256, 0, stream>>>(x_in, W0, b0, x0buf, N, 0.f, 0, 1);

  const float* xcur = x0buf;
  const float* ecur = e_in;

  for (int i = 0; i < 4; i++){
    float beta = logf(0.5f / (float)(i + 1) + 1.0f);
    float* xi_t = (i == 0) ? xS1 : (float*)xcur;
    float* xnew = (i == 3) ? out_x : ((i == 0 || i == 2) ? xS2 : xS1);
    float* ei_t = (i == 0) ? eS1 : (float*)ecur;
    float* enew = (i == 3) ? out_e : ((i == 0 || i == 2) ? eS2 : eS1);

    const float* aw1 = attn_w + (size_t)i * 256;        // aw[i,:d]
    const float* aw2 = attn_w + (size_t)i * 256 + 128;  // aw[i,d:]

    // scores: sx1 = x@aw1, sx2 = x@aw2 ; se1 = e@aw2, se2 = e@aw1
    k_scores<<<(N + 3) / 4, 256, 0, stream>>>(xcur, N, aw1, aw2, sx1, sx2);
    k_scores<<<(E + 3) / 4, 256, 0, stream>>>(ecur, E, aw2, aw1, se1, se2);

    k_softmax_v2e<<<(E + 3) / 4, 256, 0, stream>>>(nodesArr, eo, sx1, se1,
        dist_v2e, deg_v2e, attn_b, wd_w, wd_b, wg_w, wg_b, i, E, a_v2e);
    k_softmax_e2v<<<(N + 255) / 256, 256, 0, stream>>>(edgesArr, no_, perm, se2, sx2,
        dist_e2v, deg_e2v, attn_b, wd_w, wd_b, wg_w, wg_b, i, N, a_e2v);

    k_agg1<<<(E + 3) / 4, 256, 0, stream>>>(nodesArr, eo, xcur, a_v2e, degE, E, Xe1);
    k_agg2<<<(N + 3) / 4, 256, 0, stream>>>(edgesArr, no_, perm, Xe1, ecur, a_e2v,
                                            degV, x0buf, N, Xv2, xi_t);
    k_agg3<<<(E + 3) / 4, 256, 0, stream>>>(nodesArr, eo, Xv2, a_v2e, degE, Xe1, e_in, E, ei_t);

    dim3 gx((N + 63) / 64, 2), ge((E + 63) / 64, 2);
    k_gemm<<<gx, 256, 0, stream>>>(xi_t, Wn + (size_t)i * DD * DD, nullptr, xnew, N, beta, 1, i < 3 ? 1 : 0);
    k_gemm<<<ge, 256, 0, stream>>>(ei_t, We + (size_t)i * DD * DD, nullptr, enew, E, beta, 1, i < 3 ? 1 : 0);

    xcur = xnew; ecur = enew;
  }
}

// Round 3
// 1426.234 us; speedup vs baseline: 1.4550x; 1.2724x over previous
//
#include <hip/hip_runtime.h>
#include <hip/hip_fp16.h>
#include <math.h>

#define DD 128
#define SCAN_BLOCKS 256

__device__ inline float wave_sum(float v){
#pragma unroll
  for (int m = 32; m >= 1; m >>= 1) v += __shfl_xor(v, m, 64);
  return v;
}
__device__ inline float wave_max(float v){
#pragma unroll
  for (int m = 32; m >= 1; m >>= 1) v = fmaxf(v, __shfl_xor(v, m, 64));
  return v;
}
__device__ inline int wave_sum_i(int v){
#pragma unroll
  for (int m = 32; m >= 1; m >>= 1) v += __shfl_xor(v, m, 64);
  return v;
}

// ---- setup kernels -------------------------------------------------------

__global__ void k_edge_offsets(const int* __restrict__ edges, int nnz, int E,
                               int* __restrict__ eo){
  int e = blockIdx.x * blockDim.x + threadIdx.x;
  if (e > E) return;
  int lo = 0, hi = nnz;
  while (lo < hi){ int mid = (lo + hi) >> 1; if (edges[mid] < e) lo = mid + 1; else hi = mid; }
  eo[e] = lo;
}

__global__ void k_hist(const int* __restrict__ nodes, int nnz, int* __restrict__ dV){
  int k = blockIdx.x * blockDim.x + threadIdx.x;
  if (k < nnz) atomicAdd(&dV[nodes[k]], 1);
}

__global__ __launch_bounds__(256) void k_scan_partial(const int* __restrict__ dV, int N,
                                                      int* __restrict__ part){
  int b = blockIdx.x, t = threadIdx.x;
  int chunk = (N + SCAN_BLOCKS - 1) / SCAN_BLOCKS;
  int s0 = b * chunk, s1 = min(s0 + chunk, N);
  int sum = 0;
  for (int n = s0 + t; n < s1; n += 256) sum += dV[n];
  sum = wave_sum_i(sum);
  __shared__ int wred[4];
  int lane = t & 63, wid = t >> 6;
  if (lane == 0) wred[wid] = sum;
  __syncthreads();
  if (t == 0) part[b] = wred[0] + wred[1] + wred[2] + wred[3];
}

__global__ __launch_bounds__(SCAN_BLOCKS) void k_scan_blocksums(int* __restrict__ part){
  __shared__ int sh[SCAN_BLOCKS];
  int t = threadIdx.x;
  int v = part[t];
  sh[t] = v; __syncthreads();
  for (int off = 1; off < SCAN_BLOCKS; off <<= 1){
    int add = (t >= off) ? sh[t - off] : 0;
    __syncthreads();
    sh[t] += add;
    __syncthreads();
  }
  part[t] = sh[t] - v;
}

__global__ __launch_bounds__(256) void k_scan_apply(const int* __restrict__ dV, int N, int nnz,
    const int* __restrict__ partScan, int* __restrict__ no, int* __restrict__ nfill,
    float* __restrict__ degV){
  int b = blockIdx.x, t = threadIdx.x;
  int chunk = (N + SCAN_BLOCKS - 1) / SCAN_BLOCKS;
  int s0 = b * chunk, s1 = min(s0 + chunk, N);
  int lane = t & 63, wid = t >> 6;
  __shared__ int wtot[4];
  __shared__ int s_run;
  if (t == 0) s_run = partScan[b];
  __syncthreads();
  for (int base = s0; base < s1; base += 256){
    int n = base + t;
    int d = (n < s1) ? dV[n] : 0;
    int v = d;
#pragma unroll
    for (int off = 1; off < 64; off <<= 1){
      int o = __shfl_up(v, off, 64);
      if (lane >= off) v += o;
    }
    if (lane == 63) wtot[wid] = v;
    __syncthreads();
    int run0 = s_run;
    int woff = 0;
    for (int w = 0; w < wid; w++) woff += wtot[w];
    if (n < s1){
      int excl = run0 + woff + v - d;
      no[n] = excl; nfill[n] = excl;
      degV[n] = d > 0 ? 1.0f / sqrtf((float)d) : 1.0f;
    }
    int btot = wtot[0] + wtot[1] + wtot[2] + wtot[3];
    __syncthreads();
    if (t == 0) s_run = run0 + btot;
    __syncthreads();
  }
  if (b == 0 && t == 0) no[N] = nnz;
}

__global__ void k_perm(const int* __restrict__ nodes, int nnz,
                       int* __restrict__ nfill, int* __restrict__ perm){
  int k = blockIdx.x * blockDim.x + threadIdx.x;
  if (k < nnz){ int pos = atomicAdd(&nfill[nodes[k]], 1); perm[pos] = k; }
}

__global__ void k_edge_deg(const int* __restrict__ nodes, const int* __restrict__ eo, int E,
                           const int* __restrict__ dV, float* __restrict__ degE){
  int e = blockIdx.x * blockDim.x + threadIdx.x;
  if (e >= E) return;
  int b = eo[e], en = eo[e + 1];
  float s = 0.f;
  for (int k = b; k < en; k++) s += (float)dV[nodes[k]];
  float cnt = (float)(en - b);
  float dE = s / fmaxf(cnt, 1.0f);
  degE[e] = dE > 0.f ? 1.0f / sqrtf(dE) : 1.0f;
}

// f32 -> f16 converter (n half2 elements)
__global__ void k_tohalf(const float2* __restrict__ src, __half2* __restrict__ dst, int n){
  int i = blockIdx.x * blockDim.x + threadIdx.x;
  if (i < n){ float2 v = src[i]; dst[i] = __floats2half2_rn(v.x, v.y); }
}

// ---- per-layer kernels ---------------------------------------------------

// outA[r] = rows[r,:]·va ; outB[r] = rows[r,:]·vb   (wave per row, fp16 rows)
__global__ __launch_bounds__(256) void k_scores(const __half2* __restrict__ rows, int nrows,
                        const float* __restrict__ va, const float* __restrict__ vb,
                        float* __restrict__ outA, float* __restrict__ outB){
  int wave = threadIdx.x >> 6, lane = threadIdx.x & 63;
  int r = blockIdx.x * 4 + wave;
  if (r >= nrows) return;
  float2 x = __half22float2(rows[(size_t)r * 64 + lane]);
  float2 a = ((const float2*)va)[lane];
  float2 b = ((const float2*)vb)[lane];
  float s1 = x.x * a.x + x.y * a.y;
  float s2 = x.x * b.x + x.y * b.y;
  s1 = wave_sum(s1); s2 = wave_sum(s2);
  if (lane == 0){ outA[r] = s1; outB[r] = s2; }
}

// softmax over contiguous (sorted) edge segments; wave per edge
__global__ __launch_bounds__(256) void k_softmax_v2e(
    const int* __restrict__ nodes, const int* __restrict__ eo,
    const float* __restrict__ sx1, const float* __restrict__ se1,
    const float* __restrict__ dist, const float* __restrict__ deg,
    const float* __restrict__ ab, const float* __restrict__ wdw, const float* __restrict__ wdb,
    const float* __restrict__ wgw, const float* __restrict__ wgb, int li,
    int E, float* __restrict__ a_out){
  int wave = threadIdx.x >> 6, lane = threadIdx.x & 63;
  int e = blockIdx.x * 4 + wave;
  if (e >= E) return;
  int b = eo[e], en = eo[e + 1];
  if (b >= en) return;
  float base = se1[e] + ab[li] + wdb[li] + wgb[li];
  float wd = wdw[li], wg = wgw[li];
  float m = -INFINITY;
  for (int k = b + lane; k < en; k += 64){
    float s = sx1[nodes[k]] + base + dist[k] * wd + deg[k] * wg;
    a_out[k] = s;
    m = fmaxf(m, s);
  }
  m = wave_max(m);
  float sum = 0.f;
  for (int k = b + lane; k < en; k += 64){
    float ex = expf(a_out[k] - m);
    a_out[k] = ex; sum += ex;
  }
  sum = wave_sum(sum);
  for (int k = b + lane; k < en; k += 64) a_out[k] = a_out[k] / sum;
}

// pass1: Xe1[e,:] = degE[e] * sum_k a_v2e[k]*x[nodes[k],:]   (wave per edge, fp16)
__global__ __launch_bounds__(256) void k_agg1(const int* __restrict__ nodes, const int* __restrict__ eo,
    const __half2* __restrict__ xh, const float* __restrict__ a_v2e, const float* __restrict__ degE,
    int E, __half2* __restrict__ Xe1h){
  int wave = threadIdx.x >> 6, lane = threadIdx.x & 63;
  int e = blockIdx.x * 4 + wave;
  if (e >= E) return;
  int b = eo[e], en = eo[e + 1];
  float2 acc = make_float2(0.f, 0.f);
  for (int k = b; k < en; k++){
    int n = nodes[k];
    float w = a_v2e[k];
    float2 v = __half22float2(xh[(size_t)n * 64 + lane]);
    acc.x += w * v.x; acc.y += w * v.y;
  }
  float dE = degE[e];
  Xe1h[(size_t)e * 64 + lane] = __floats2half2_rn(acc.x * dE, acc.y * dE);
}

// pass2 FUSED with e2v softmax: per node (wave), lane-parallel segment softmax
// over incident edges, then weighted aggregation of Xe1h and eh rows.
// writes Xv2h (fp16) and xi = 0.45*(Xv1+Xv2)+0.1*x0 (f32)
__global__ __launch_bounds__(256) void k_agg2f(
    const int* __restrict__ edges, const int* __restrict__ no, const int* __restrict__ perm,
    const float* __restrict__ se2, const float* __restrict__ sx2,
    const float* __restrict__ dist, const float* __restrict__ deg,
    const float* __restrict__ ab, const float* __restrict__ wdw, const float* __restrict__ wdb,
    const float* __restrict__ wgw, const float* __restrict__ wgb, int li,
    const __half2* __restrict__ Xe1h, const __half2* __restrict__ eh,
    const float* __restrict__ degV, const float* __restrict__ x0,
    int N, __half2* __restrict__ Xv2h, float* __restrict__ xi){
  int wave = threadIdx.x >> 6, lane = threadIdx.x & 63;
  int n = blockIdx.x * 4 + wave;
  if (n >= N) return;
  int b = no[n], en = no[n + 1];
  float base = sx2[n] + ab[li] + wdb[li] + wgb[li];
  float wd = wdw[li], wg = wgw[li];
  float m_run = -INFINITY, l_run = 0.f;
  float2 a1 = make_float2(0.f, 0.f), a2 = make_float2(0.f, 0.f);
  for (int cb = b; cb < en; cb += 64){
    int cs = min(64, en - cb);
    float s = -INFINITY; int e_l = 0;
    if (lane < cs){
      int k = perm[cb + lane];
      e_l = edges[k];
      s = se2[e_l] + base + dist[k] * wd + deg[k] * wg;
    }
    float m_c = wave_max(s);
    float p = (lane < cs) ? expf(s - m_c) : 0.f;
    float l_c = wave_sum(p);
    float m_new = fmaxf(m_run, m_c);
    float f_old = expf(m_run - m_new);   // 0 on first chunk (m_run=-inf)
    float f_c = expf(m_c - m_new);
    a1.x *= f_old; a1.y *= f_old; a2.x *= f_old; a2.y *= f_old;
    l_run = l_run * f_old + l_c * f_c;
    m_run = m_new;
    for (int jj = 0; jj < cs; jj++){
      float w = __shfl(p, jj, 64) * f_c;
      int e = __shfl(e_l, jj, 64);
      float2 v1 = __half22float2(Xe1h[(size_t)e * 64 + lane]);
      float2 v2 = __half22float2(eh[(size_t)e * 64 + lane]);
      a1.x += w * v1.x; a1.y += w * v1.y;
      a2.x += w * v2.x; a2.y += w * v2.y;
    }
  }
  float inv = l_run > 0.f ? 1.0f / l_run : 0.f;
  float dv = degV[n] * inv;
  float2 xv1 = make_float2(a1.x * dv, a1.y * dv);
  float2 xv2 = make_float2(a2.x * dv, a2.y * dv);
  Xv2h[(size_t)n * 64 + lane] = __floats2half2_rn(xv2.x, xv2.y);
  float2 x0v = *((const float2*)(x0 + (size_t)n * DD) + lane);
  float2 o = make_float2(0.45f * (xv1.x + xv2.x) + 0.1f * x0v.x,
                         0.45f * (xv1.y + xv2.y) + 0.1f * x0v.y);
  *((float2*)(xi + (size_t)n * DD) + lane) = o;
}

// pass3: per edge: Xe2 = degE*sum a_v2e*Xv2[node]; ei = 0.45*(Xe1+Xe2)+0.1*e0
__global__ __launch_bounds__(256) void k_agg3(const int* __restrict__ nodes, const int* __restrict__ eo,
    const __half2* __restrict__ Xv2h, const float* __restrict__ a_v2e, const float* __restrict__ degE,
    const __half2* __restrict__ Xe1h, const float* __restrict__ e0,
    int E, float* __restrict__ ei){
  int wave = threadIdx.x >> 6, lane = threadIdx.x & 63;
  int e = blockIdx.x * 4 + wave;
  if (e >= E) return;
  int b = eo[e], en = eo[e + 1];
  float2 acc = make_float2(0.f, 0.f);
  for (int k = b; k < en; k++){
    int n = nodes[k];
    float w = a_v2e[k];
    float2 v = __half22float2(Xv2h[(size_t)n * 64 + lane]);
    acc.x += w * v.x; acc.y += w * v.y;
  }
  float dE = degE[e];
  float2 xe1 = __half22float2(Xe1h[(size_t)e * 64 + lane]);
  float2 e0v = *((const float2*)(e0 + (size_t)e * DD) + lane);
  float2 o = make_float2(0.45f * (xe1.x + acc.x * dE) + 0.1f * e0v.x,
                         0.45f * (xe1.y + acc.y * dE) + 0.1f * e0v.y);
  *((float2*)(ei + (size_t)e * DD) + lane) = o;
}

// GEMM: out[r,c] = epilogue( sum_k A[r,k] * W[k,c] ), optional fp16 dual write
__global__ __launch_bounds__(256) void k_gemm(const float* __restrict__ A, const float* __restrict__ W,
    const float* __restrict__ bias, float* __restrict__ out, __half2* __restrict__ outh,
    int nrows, float beta, int mode, int do_relu){
  __shared__ float As[32][68];
  __shared__ float Bs[32][64];
  int row0 = blockIdx.x * 64, col0 = blockIdx.y * 64;
  int tid = threadIdx.x;
  int tc = (tid & 15) * 4, tr = (tid >> 4) * 4;
  float acc[4][4] = {};
  for (int kt = 0; kt < 4; kt++){
#pragma unroll
    for (int i = 0; i < 2; i++){
      int f4 = tid + i * 256; int flat = f4 * 4;
      int r = flat >> 5, k = flat & 31;
      int gr = row0 + r;
      float4 v = make_float4(0.f, 0.f, 0.f, 0.f);
      if (gr < nrows) v = *(const float4*)(A + (size_t)gr * 128 + kt * 32 + k);
      As[k][r] = v.x; As[k + 1][r] = v.y; As[k + 2][r] = v.z; As[k + 3][r] = v.w;
    }
#pragma unroll
    for (int i = 0; i < 2; i++){
      int f4 = tid + i * 256; int flat = f4 * 4;
      int k = flat >> 6, c = flat & 63;
      *(float4*)&Bs[k][c] = *(const float4*)(W + (size_t)(kt * 32 + k) * 128 + col0 + c);
    }
    __syncthreads();
#pragma unroll 8
    for (int k = 0; k < 32; k++){
      float4 a = *(const float4*)&As[k][tr];
      float4 b = *(const float4*)&Bs[k][tc];
      float av[4] = {a.x, a.y, a.z, a.w};
      float bv[4] = {b.x, b.y, b.z, b.w};
#pragma unroll
      for (int ii = 0; ii < 4; ii++)
#pragma unroll
        for (int j = 0; j < 4; j++) acc[ii][j] += av[ii] * bv[j];
    }
    __syncthreads();
  }
#pragma unroll
  for (int ii = 0; ii < 4; ii++){
    int gr = row0 + tr + ii;
    if (gr >= nrows) continue;
    float ov[4];
    if (mode == 0){
#pragma unroll
      for (int j = 0; j < 4; j++){
        float v = acc[ii][j] + bias[col0 + tc + j];
        ov[j] = fmaxf(v, 0.f);
      }
    } else {
      float4 av4 = *(const float4*)(A + (size_t)gr * 128 + col0 + tc);
      float avv[4] = {av4.x, av4.y, av4.z, av4.w};
#pragma unroll
      for (int j = 0; j < 4; j++){
        float v = (1.0f - beta) * avv[j] + beta * acc[ii][j];
        if (do_relu) v = fmaxf(v, 0.f);
        ov[j] = v;
      }
    }
    *(float4*)(out + (size_t)gr * 128 + col0 + tc) = make_float4(ov[0], ov[1], ov[2], ov[3]);
    if (outh){
      size_t hb = (size_t)gr * 64 + (col0 + tc) / 2;
      outh[hb]     = __floats2half2_rn(ov[0], ov[1]);
      outh[hb + 1] = __floats2half2_rn(ov[2], ov[3]);
    }
  }
}

// ---- host ----------------------------------------------------------------

extern "C" void kernel_launch(void* const* d_in, const int* in_sizes, int n_in,
                              void* d_out, int out_size, void* d_ws, size_t ws_size,
                              hipStream_t stream) {
  const float* x_in     = (const float*)d_in[0];
  const float* e_in     = (const float*)d_in[1];
  const int*   hei      = (const int*)d_in[2];
  const float* dist_v2e = (const float*)d_in[3];
  const float* deg_v2e  = (const float*)d_in[4];
  const float* dist_e2v = (const float*)d_in[5];
  const float* deg_e2v  = (const float*)d_in[6];
  const float* W0       = (const float*)d_in[7];
  const float* b0       = (const float*)d_in[8];
  const float* Wn       = (const float*)d_in[9];
  const float* We       = (const float*)d_in[10];
  const float* attn_w   = (const float*)d_in[11];
  const float* attn_b   = (const float*)d_in[12];
  const float* wd_w     = (const float*)d_in[13];
  const float* wd_b     = (const float*)d_in[14];
  const float* wg_w     = (const float*)d_in[15];
  const float* wg_b     = (const float*)d_in[16];

  const int N   = in_sizes[0] / DD;
  const int E   = in_sizes[1] / DD;
  const int NNZ = in_sizes[2] / 2;
  const int* nodesArr = hei;
  const int* edgesArr = hei + NNZ;

  float* out_x = (float*)d_out;
  float* out_e = (float*)d_out + (size_t)N * DD;

  // fp16 aliases inside d_out regions (fully overwritten by final GEMMs):
  // out_x (N*128*4 B): [Xv2h: N*128*2 B][xh: N*128*2 B]
  // out_e (E*128*4 B): [Xe1h: E*128*2 B][eh: E*128*2 B]
  __half2* Xv2h = (__half2*)out_x;
  __half2* xh   = (__half2*)((char*)out_x + (size_t)N * DD * 2);
  __half2* Xe1h = (__half2*)out_e;
  __half2* eh   = (__half2*)((char*)out_e + (size_t)E * DD * 2);

  char* wsp = (char*)d_ws;
  auto alloc = [&](size_t bytes) -> void* {
    void* p = (void*)wsp;
    wsp += (bytes + 255) / 256 * 256;
    return p;
  };
  float* x0buf = (float*)alloc((size_t)N * DD * 4);
  float* xS1   = (float*)alloc((size_t)N * DD * 4);
  float* xS2   = (float*)alloc((size_t)N * DD * 4);
  float* eS1   = (float*)alloc((size_t)E * DD * 4);
  float* eS2   = (float*)alloc((size_t)E * DD * 4);
  float* sx1   = (float*)alloc((size_t)N * 4);
  float* sx2   = (float*)alloc((size_t)N * 4);
  float* se1   = (float*)alloc((size_t)E * 4);
  float* se2   = (float*)alloc((size_t)E * 4);
  float* a_v2e = (float*)alloc((size_t)NNZ * 4);
  float* degV  = (float*)alloc((size_t)N * 4);
  float* degE  = (float*)alloc((size_t)E * 4);
  int* dV_i  = (int*)alloc((size_t)N * 4);
  int* no_   = (int*)alloc((size_t)(N + 1) * 4);
  int* nfill = (int*)alloc((size_t)N * 4);
  int* perm  = (int*)alloc((size_t)NNZ * 4);
  int* eo    = (int*)alloc((size_t)(E + 1) * 4);
  int* part  = (int*)alloc((size_t)SCAN_BLOCKS * 4);

  // ---- setup
  hipMemsetAsync(dV_i, 0, (size_t)N * 4, stream);
  k_edge_offsets<<<(E + 1 + 255) / 256, 256, 0, stream>>>(edgesArr, NNZ, E, eo);
  k_hist<<<(NNZ + 255) / 256, 256, 0, stream>>>(nodesArr, NNZ, dV_i);
  k_scan_partial<<<SCAN_BLOCKS, 256, 0, stream>>>(dV_i, N, part);
  k_scan_blocksums<<<1, SCAN_BLOCKS, 0, stream>>>(part);
  k_scan_apply<<<SCAN_BLOCKS, 256, 0, stream>>>(dV_i, N, NNZ, part, no_, nfill, degV);
  k_perm<<<(NNZ + 255) / 256, 256, 0, stream>>>(nodesArr, NNZ, nfill, perm);
  k_edge_deg<<<(E + 255) / 256, 256, 0, stream>>>(nodesArr, eo, E, dV_i, degE);

  // e fp16 copy
  k_tohalf<<<((E * 64) + 255) / 256, 256, 0, stream>>>((const float2*)e_in, eh, E * 64);

  // x0 = relu(x @ W0 + b0), dual write xh
  dim3 g0((N + 63) / 64, 2);
  k_gemm<<<g0, 256, 0, stream>>>(x_in, W0, b0, x0buf, xh, N, 0.f, 0, 1);

  const float* xcur = x0buf;
  const float* ecur = e_in;

  for (int i = 0; i < 4; i++){
    float beta = logf(0.5f / (float)(i + 1) + 1.0f);
    float* xi_t = (i == 0) ? xS1 : (float*)xcur;
    float* xnew = (i == 3) ? out_x : ((i == 0 || i == 2) ? xS2 : xS1);
    float* ei_t = (i == 0) ? eS1 : (float*)ecur;
    float* enew = (i == 3) ? out_e : ((i == 0 || i == 2) ? eS2 : eS1);

    const float* aw1 = attn_w + (size_t)i * 256;        // aw[i,:d]
    const float* aw2 = attn_w + (size_t)i * 256 + 128;  // aw[i,d:]

    k_scores<<<(N + 3) / 4, 256, 0, stream>>>(xh, N, aw1, aw2, sx1, sx2);
    k_scores<<<(E + 3) / 4, 256, 0, stream>>>(eh, E, aw2, aw1, se1, se2);

    k_softmax_v2e<<<(E + 3) / 4, 256, 0, stream>>>(nodesArr, eo, sx1, se1,
        dist_v2e, deg_v2e, attn_b, wd_w, wd_b, wg_w, wg_b, i, E, a_v2e);

    k_agg1<<<(E + 3) / 4, 256, 0, stream>>>(nodesArr, eo, xh, a_v2e, degE, E, Xe1h);
    k_agg2f<<<(N + 3) / 4, 256, 0, stream>>>(edgesArr, no_, perm, se2, sx2,
        dist_e2v, deg_e2v, attn_b, wd_w, wd_b, wg_w, wg_b, i,
        Xe1h, eh, degV, x0buf, N, Xv2h, xi_t);
    k_agg3<<<(E + 3) / 4, 256, 0, stream>>>(nodesArr, eo, Xv2h, a_v2e, degE, Xe1h, e_in, E, ei_t);

    dim3 gx((N + 63) / 64, 2), ge((E + 63) / 64, 2);
    k_gemm<<<gx, 256, 0, stream>>>(xi_t, Wn + (size_t)i * DD * DD, nullptr, xnew,
                                   (i == 3) ? nullptr : xh, N, beta, 1, i < 3 ? 1 : 0);
    k_gemm<<<ge, 256, 0, stream>>>(ei_t, We + (size_t)i * DD * DD, nullptr, enew,
                                   (i == 3) ? nullptr : eh, E, beta, 1, i < 3 ? 1 : 0);

    xcur = xnew; ecur = enew;
  }
}

// Round 4
// 1139.540 us; speedup vs baseline: 1.8210x; 1.2516x over previous
//
#include <hip/hip_runtime.h>
#include <hip/hip_fp16.h>
#include <math.h>

#define DD 128
#define SCAN_BLOCKS 256

__device__ inline float wave_sum(float v){
#pragma unroll
  for (int m = 32; m >= 1; m >>= 1) v += __shfl_xor(v, m, 64);
  return v;
}
__device__ inline float wave_max(float v){
#pragma unroll
  for (int m = 32; m >= 1; m >>= 1) v = fmaxf(v, __shfl_xor(v, m, 64));
  return v;
}
__device__ inline int wave_sum_i(int v){
#pragma unroll
  for (int m = 32; m >= 1; m >>= 1) v += __shfl_xor(v, m, 64);
  return v;
}

// ---- setup kernels -------------------------------------------------------

__global__ void k_edge_offsets(const int* __restrict__ edges, int nnz, int E,
                               int* __restrict__ eo){
  int e = blockIdx.x * blockDim.x + threadIdx.x;
  if (e > E) return;
  int lo = 0, hi = nnz;
  while (lo < hi){ int mid = (lo + hi) >> 1; if (edges[mid] < e) lo = mid + 1; else hi = mid; }
  eo[e] = lo;
}

__global__ void k_hist(const int* __restrict__ nodes, int nnz, int* __restrict__ dV){
  int k = blockIdx.x * blockDim.x + threadIdx.x;
  if (k < nnz) atomicAdd(&dV[nodes[k]], 1);
}

__global__ __launch_bounds__(256) void k_scan_partial(const int* __restrict__ dV, int N,
                                                      int* __restrict__ part){
  int b = blockIdx.x, t = threadIdx.x;
  int chunk = (N + SCAN_BLOCKS - 1) / SCAN_BLOCKS;
  int s0 = b * chunk, s1 = min(s0 + chunk, N);
  int sum = 0;
  for (int n = s0 + t; n < s1; n += 256) sum += dV[n];
  sum = wave_sum_i(sum);
  __shared__ int wred[4];
  int lane = t & 63, wid = t >> 6;
  if (lane == 0) wred[wid] = sum;
  __syncthreads();
  if (t == 0) part[b] = wred[0] + wred[1] + wred[2] + wred[3];
}

__global__ __launch_bounds__(SCAN_BLOCKS) void k_scan_blocksums(int* __restrict__ part){
  __shared__ int sh[SCAN_BLOCKS];
  int t = threadIdx.x;
  int v = part[t];
  sh[t] = v; __syncthreads();
  for (int off = 1; off < SCAN_BLOCKS; off <<= 1){
    int add = (t >= off) ? sh[t - off] : 0;
    __syncthreads();
    sh[t] += add;
    __syncthreads();
  }
  part[t] = sh[t] - v;
}

__global__ __launch_bounds__(256) void k_scan_apply(const int* __restrict__ dV, int N, int nnz,
    const int* __restrict__ partScan, int* __restrict__ no, int* __restrict__ nfill,
    float* __restrict__ degV){
  int b = blockIdx.x, t = threadIdx.x;
  int chunk = (N + SCAN_BLOCKS - 1) / SCAN_BLOCKS;
  int s0 = b * chunk, s1 = min(s0 + chunk, N);
  int lane = t & 63, wid = t >> 6;
  __shared__ int wtot[4];
  __shared__ int s_run;
  if (t == 0) s_run = partScan[b];
  __syncthreads();
  for (int base = s0; base < s1; base += 256){
    int n = base + t;
    int d = (n < s1) ? dV[n] : 0;
    int v = d;
#pragma unroll
    for (int off = 1; off < 64; off <<= 1){
      int o = __shfl_up(v, off, 64);
      if (lane >= off) v += o;
    }
    if (lane == 63) wtot[wid] = v;
    __syncthreads();
    int run0 = s_run;
    int woff = 0;
    for (int w = 0; w < wid; w++) woff += wtot[w];
    if (n < s1){
      int excl = run0 + woff + v - d;
      no[n] = excl; nfill[n] = excl;
      degV[n] = d > 0 ? 1.0f / sqrtf((float)d) : 1.0f;
    }
    int btot = wtot[0] + wtot[1] + wtot[2] + wtot[3];
    __syncthreads();
    if (t == 0) s_run = run0 + btot;
    __syncthreads();
  }
  if (b == 0 && t == 0) no[N] = nnz;
}

__global__ void k_perm(const int* __restrict__ nodes, int nnz,
                       int* __restrict__ nfill, int* __restrict__ perm){
  int k = blockIdx.x * blockDim.x + threadIdx.x;
  if (k < nnz){ int pos = atomicAdd(&nfill[nodes[k]], 1); perm[pos] = k; }
}

// pack[j] = {edges[perm[j]] as float-bits, dist_e2v[perm[j]], deg_e2v[perm[j]], 0}
__global__ void k_pack(const int* __restrict__ perm, const int* __restrict__ edges,
                       const float* __restrict__ dist, const float* __restrict__ deg,
                       int nnz, float4* __restrict__ pack){
  int j = blockIdx.x * blockDim.x + threadIdx.x;
  if (j < nnz){
    int k = perm[j];
    pack[j] = make_float4(__int_as_float(edges[k]), dist[k], deg[k], 0.f);
  }
}

__global__ void k_edge_deg(const int* __restrict__ nodes, const int* __restrict__ eo, int E,
                           const int* __restrict__ dV, float* __restrict__ degE){
  int e = blockIdx.x * blockDim.x + threadIdx.x;
  if (e >= E) return;
  int b = eo[e], en = eo[e + 1];
  float s = 0.f;
  for (int k = b; k < en; k++) s += (float)dV[nodes[k]];
  float cnt = (float)(en - b);
  float dE = s / fmaxf(cnt, 1.0f);
  degE[e] = dE > 0.f ? 1.0f / sqrtf(dE) : 1.0f;
}

// f32 -> f16 into interleaved ET .y slots (n half2 elements)
__global__ void k_tohalf_et(const float2* __restrict__ src, __half2* __restrict__ ET, int n){
  int i = blockIdx.x * blockDim.x + threadIdx.x;
  if (i < n){ float2 v = src[i]; ET[(size_t)i * 2 + 1] = __floats2half2_rn(v.x, v.y); }
}

// ---- per-layer kernels ---------------------------------------------------

// linear fp16 rows (xh)
__global__ __launch_bounds__(256) void k_scores(const __half2* __restrict__ rows, int nrows,
                        const float* __restrict__ va, const float* __restrict__ vb,
                        float* __restrict__ outA, float* __restrict__ outB){
  int wave = threadIdx.x >> 6, lane = threadIdx.x & 63;
  int r = blockIdx.x * 4 + wave;
  if (r >= nrows) return;
  float2 x = __half22float2(rows[(size_t)r * 64 + lane]);
  float2 a = ((const float2*)va)[lane];
  float2 b = ((const float2*)vb)[lane];
  float s1 = x.x * a.x + x.y * a.y;
  float s2 = x.x * b.x + x.y * b.y;
  s1 = wave_sum(s1); s2 = wave_sum(s2);
  if (lane == 0){ outA[r] = s1; outB[r] = s2; }
}

// interleaved ET rows, use .y (= eh)
__global__ __launch_bounds__(256) void k_scores_et(const float2* __restrict__ ETp, int nrows,
                        const float* __restrict__ va, const float* __restrict__ vb,
                        float* __restrict__ outA, float* __restrict__ outB){
  int wave = threadIdx.x >> 6, lane = threadIdx.x & 63;
  int r = blockIdx.x * 4 + wave;
  if (r >= nrows) return;
  float2 q = ETp[(size_t)r * 64 + lane];
  float2 x = __half22float2(*(__half2*)&q.y);
  float2 a = ((const float2*)va)[lane];
  float2 b = ((const float2*)vb)[lane];
  float s1 = x.x * a.x + x.y * a.y;
  float s2 = x.x * b.x + x.y * b.y;
  s1 = wave_sum(s1); s2 = wave_sum(s2);
  if (lane == 0){ outA[r] = s1; outB[r] = s2; }
}

// softmax over contiguous (sorted) edge segments; wave per edge
__global__ __launch_bounds__(256) void k_softmax_v2e(
    const int* __restrict__ nodes, const int* __restrict__ eo,
    const float* __restrict__ sx1, const float* __restrict__ se1,
    const float* __restrict__ dist, const float* __restrict__ deg,
    const float* __restrict__ ab, const float* __restrict__ wdw, const float* __restrict__ wdb,
    const float* __restrict__ wgw, const float* __restrict__ wgb, int li,
    int E, float* __restrict__ a_out){
  int wave = threadIdx.x >> 6, lane = threadIdx.x & 63;
  int e = blockIdx.x * 4 + wave;
  if (e >= E) return;
  int b = eo[e], en = eo[e + 1];
  if (b >= en) return;
  float base = se1[e] + ab[li] + wdb[li] + wgb[li];
  float wd = wdw[li], wg = wgw[li];
  float m = -INFINITY;
  for (int k = b + lane; k < en; k += 64){
    float s = sx1[nodes[k]] + base + dist[k] * wd + deg[k] * wg;
    a_out[k] = s;
    m = fmaxf(m, s);
  }
  m = wave_max(m);
  float sum = 0.f;
  for (int k = b + lane; k < en; k += 64){
    float ex = expf(a_out[k] - m);
    a_out[k] = ex; sum += ex;
  }
  sum = wave_sum(sum);
  for (int k = b + lane; k < en; k += 64) a_out[k] = a_out[k] / sum;
}

// pass1: ET[e].x-slots = degE[e] * sum_k a_v2e[k]*xh[nodes[k],:]  (wave per edge, 8x unroll)
__global__ __launch_bounds__(256) void k_agg1(const int* __restrict__ nodes, const int* __restrict__ eo,
    const __half2* __restrict__ xh, const float* __restrict__ a_v2e, const float* __restrict__ degE,
    int E, __half2* __restrict__ ET){
  int wave = threadIdx.x >> 6, lane = threadIdx.x & 63;
  int e = blockIdx.x * 4 + wave;
  if (e >= E) return;
  int b = eo[e], en = eo[e + 1];
  float2 acc = make_float2(0.f, 0.f);
  int k = b;
  for (; k + 7 < en; k += 8){
    int n[8]; float w[8]; float2 v[8];
#pragma unroll
    for (int u = 0; u < 8; u++){ n[u] = nodes[k + u]; w[u] = a_v2e[k + u]; }
#pragma unroll
    for (int u = 0; u < 8; u++) v[u] = __half22float2(xh[(size_t)n[u] * 64 + lane]);
#pragma unroll
    for (int u = 0; u < 8; u++){ acc.x += w[u] * v[u].x; acc.y += w[u] * v[u].y; }
  }
  for (; k < en; k++){
    int n = nodes[k];
    float w = a_v2e[k];
    float2 v = __half22float2(xh[(size_t)n * 64 + lane]);
    acc.x += w * v.x; acc.y += w * v.y;
  }
  float dE = degE[e];
  ET[((size_t)e * 64 + lane) * 2] = __floats2half2_rn(acc.x * dE, acc.y * dE);
}

// pass2 FUSED with e2v softmax: wave per node; packed CSR payload; interleaved ET loads
__global__ __launch_bounds__(256) void k_agg2f(
    const float4* __restrict__ pack, const int* __restrict__ no,
    const float* __restrict__ se2, const float* __restrict__ sx2,
    const float* __restrict__ ab, const float* __restrict__ wdw, const float* __restrict__ wdb,
    const float* __restrict__ wgw, const float* __restrict__ wgb, int li,
    const float2* __restrict__ ETp,
    const float* __restrict__ degV, const float* __restrict__ x0,
    int N, __half2* __restrict__ Xv2h, float* __restrict__ xi){
  int wave = threadIdx.x >> 6, lane = threadIdx.x & 63;
  int n = blockIdx.x * 4 + wave;
  if (n >= N) return;
  int b = no[n], en = no[n + 1];
  float base = sx2[n] + ab[li] + wdb[li] + wgb[li];
  float wd = wdw[li], wg = wgw[li];
  float m_run = -INFINITY, l_run = 0.f;
  float2 a1 = make_float2(0.f, 0.f), a2 = make_float2(0.f, 0.f);
  for (int cb = b; cb < en; cb += 64){
    int cs = min(64, en - cb);
    float s = -INFINITY; int e_l = 0;
    if (lane < cs){
      float4 pk = pack[cb + lane];
      e_l = __float_as_int(pk.x);
      s = se2[e_l] + base + pk.y * wd + pk.z * wg;
    }
    float m_c = wave_max(s);
    float p = (lane < cs) ? expf(s - m_c) : 0.f;
    float l_c = wave_sum(p);
    float m_new = fmaxf(m_run, m_c);
    float f_old = expf(m_run - m_new);
    float f_c = expf(m_c - m_new);
    a1.x *= f_old; a1.y *= f_old; a2.x *= f_old; a2.y *= f_old;
    l_run = l_run * f_old + l_c * f_c;
    m_run = m_new;
    int jj = 0;
    for (; jj + 3 < cs; jj += 4){
      float w0 = __shfl(p, jj, 64) * f_c;
      float w1 = __shfl(p, jj + 1, 64) * f_c;
      float w2 = __shfl(p, jj + 2, 64) * f_c;
      float w3 = __shfl(p, jj + 3, 64) * f_c;
      int e0 = __shfl(e_l, jj, 64);
      int e1 = __shfl(e_l, jj + 1, 64);
      int e2 = __shfl(e_l, jj + 2, 64);
      int e3 = __shfl(e_l, jj + 3, 64);
      float2 q0 = ETp[(size_t)e0 * 64 + lane];
      float2 q1 = ETp[(size_t)e1 * 64 + lane];
      float2 q2 = ETp[(size_t)e2 * 64 + lane];
      float2 q3 = ETp[(size_t)e3 * 64 + lane];
      float2 x0v, e0v;
      x0v = __half22float2(*(__half2*)&q0.x); e0v = __half22float2(*(__half2*)&q0.y);
      a1.x += w0 * x0v.x; a1.y += w0 * x0v.y; a2.x += w0 * e0v.x; a2.y += w0 * e0v.y;
      x0v = __half22float2(*(__half2*)&q1.x); e0v = __half22float2(*(__half2*)&q1.y);
      a1.x += w1 * x0v.x; a1.y += w1 * x0v.y; a2.x += w1 * e0v.x; a2.y += w1 * e0v.y;
      x0v = __half22float2(*(__half2*)&q2.x); e0v = __half22float2(*(__half2*)&q2.y);
      a1.x += w2 * x0v.x; a1.y += w2 * x0v.y; a2.x += w2 * e0v.x; a2.y += w2 * e0v.y;
      x0v = __half22float2(*(__half2*)&q3.x); e0v = __half22float2(*(__half2*)&q3.y);
      a1.x += w3 * x0v.x; a1.y += w3 * x0v.y; a2.x += w3 * e0v.x; a2.y += w3 * e0v.y;
    }
    for (; jj < cs; jj++){
      float w = __shfl(p, jj, 64) * f_c;
      int e = __shfl(e_l, jj, 64);
      float2 q = ETp[(size_t)e * 64 + lane];
      float2 v1 = __half22float2(*(__half2*)&q.x);
      float2 v2 = __half22float2(*(__half2*)&q.y);
      a1.x += w * v1.x; a1.y += w * v1.y;
      a2.x += w * v2.x; a2.y += w * v2.y;
    }
  }
  float inv = l_run > 0.f ? 1.0f / l_run : 0.f;
  float dv = degV[n] * inv;
  float2 xv1 = make_float2(a1.x * dv, a1.y * dv);
  float2 xv2 = make_float2(a2.x * dv, a2.y * dv);
  Xv2h[(size_t)n * 64 + lane] = __floats2half2_rn(xv2.x, xv2.y);
  float2 x0v = *((const float2*)(x0 + (size_t)n * DD) + lane);
  float2 o = make_float2(0.45f * (xv1.x + xv2.x) + 0.1f * x0v.x,
                         0.45f * (xv1.y + xv2.y) + 0.1f * x0v.y);
  *((float2*)(xi + (size_t)n * DD) + lane) = o;
}

// pass3: per edge: Xe2 = degE*sum a_v2e*Xv2[node]; ei = 0.45*(Xe1+Xe2)+0.1*e0  (8x unroll)
__global__ __launch_bounds__(256) void k_agg3(const int* __restrict__ nodes, const int* __restrict__ eo,
    const __half2* __restrict__ Xv2h, const float* __restrict__ a_v2e, const float* __restrict__ degE,
    const float2* __restrict__ ETp, const float* __restrict__ e0,
    int E, float* __restrict__ ei){
  int wave = threadIdx.x >> 6, lane = threadIdx.x & 63;
  int e = blockIdx.x * 4 + wave;
  if (e >= E) return;
  int b = eo[e], en = eo[e + 1];
  float2 acc = make_float2(0.f, 0.f);
  int k = b;
  for (; k + 7 < en; k += 8){
    int n[8]; float w[8]; float2 v[8];
#pragma unroll
    for (int u = 0; u < 8; u++){ n[u] = nodes[k + u]; w[u] = a_v2e[k + u]; }
#pragma unroll
    for (int u = 0; u < 8; u++) v[u] = __half22float2(Xv2h[(size_t)n[u] * 64 + lane]);
#pragma unroll
    for (int u = 0; u < 8; u++){ acc.x += w[u] * v[u].x; acc.y += w[u] * v[u].y; }
  }
  for (; k < en; k++){
    int n = nodes[k];
    float w = a_v2e[k];
    float2 v = __half22float2(Xv2h[(size_t)n * 64 + lane]);
    acc.x += w * v.x; acc.y += w * v.y;
  }
  float dE = degE[e];
  float2 q = ETp[(size_t)e * 64 + lane];
  float2 xe1 = __half22float2(*(__half2*)&q.x);
  float2 e0v = *((const float2*)(e0 + (size_t)e * DD) + lane);
  float2 o = make_float2(0.45f * (xe1.x + acc.x * dE) + 0.1f * e0v.x,
                         0.45f * (xe1.y + acc.y * dE) + 0.1f * e0v.y);
  *((float2*)(ei + (size_t)e * DD) + lane) = o;
}

// GEMM: out[r,c] = epilogue( sum_k A[r,k] * W[k,c] )
// dual fp16 write: et=0 -> linear half2 (xh); et=1 -> interleaved ET .y slots
__global__ __launch_bounds__(256) void k_gemm(const float* __restrict__ A, const float* __restrict__ W,
    const float* __restrict__ bias, float* __restrict__ out, __half2* __restrict__ outh,
    int et, int nrows, float beta, int mode, int do_relu){
  __shared__ float As[32][68];
  __shared__ float Bs[32][64];
  int row0 = blockIdx.x * 64, col0 = blockIdx.y * 64;
  int tid = threadIdx.x;
  int tc = (tid & 15) * 4, tr = (tid >> 4) * 4;
  float acc[4][4] = {};
  for (int kt = 0; kt < 4; kt++){
#pragma unroll
    for (int i = 0; i < 2; i++){
      int f4 = tid + i * 256; int flat = f4 * 4;
      int r = flat >> 5, k = flat & 31;
      int gr = row0 + r;
      float4 v = make_float4(0.f, 0.f, 0.f, 0.f);
      if (gr < nrows) v = *(const float4*)(A + (size_t)gr * 128 + kt * 32 + k);
      As[k][r] = v.x; As[k + 1][r] = v.y; As[k + 2][r] = v.z; As[k + 3][r] = v.w;
    }
#pragma unroll
    for (int i = 0; i < 2; i++){
      int f4 = tid + i * 256; int flat = f4 * 4;
      int k = flat >> 6, c = flat & 63;
      *(float4*)&Bs[k][c] = *(const float4*)(W + (size_t)(kt * 32 + k) * 128 + col0 + c);
    }
    __syncthreads();
#pragma unroll 8
    for (int k = 0; k < 32; k++){
      float4 a = *(const float4*)&As[k][tr];
      float4 b = *(const float4*)&Bs[k][tc];
      float av[4] = {a.x, a.y, a.z, a.w};
      float bv[4] = {b.x, b.y, b.z, b.w};
#pragma unroll
      for (int ii = 0; ii < 4; ii++)
#pragma unroll
        for (int j = 0; j < 4; j++) acc[ii][j] += av[ii] * bv[j];
    }
    __syncthreads();
  }
#pragma unroll
  for (int ii = 0; ii < 4; ii++){
    int gr = row0 + tr + ii;
    if (gr >= nrows) continue;
    float ov[4];
    if (mode == 0){
#pragma unroll
      for (int j = 0; j < 4; j++){
        float v = acc[ii][j] + bias[col0 + tc + j];
        ov[j] = fmaxf(v, 0.f);
      }
    } else {
      float4 av4 = *(const float4*)(A + (size_t)gr * 128 + col0 + tc);
      float avv[4] = {av4.x, av4.y, av4.z, av4.w};
#pragma unroll
      for (int j = 0; j < 4; j++){
        float v = (1.0f - beta) * avv[j] + beta * acc[ii][j];
        if (do_relu) v = fmaxf(v, 0.f);
        ov[j] = v;
      }
    }
    *(float4*)(out + (size_t)gr * 128 + col0 + tc) = make_float4(ov[0], ov[1], ov[2], ov[3]);
    if (outh){
      int cp = (col0 + tc) >> 1;
      __half2 h01 = __floats2half2_rn(ov[0], ov[1]);
      __half2 h23 = __floats2half2_rn(ov[2], ov[3]);
      if (et){
        size_t s0 = ((size_t)gr * 64 + cp) * 2 + 1;
        outh[s0] = h01; outh[s0 + 2] = h23;
      } else {
        size_t hb = (size_t)gr * 64 + cp;
        outh[hb] = h01; outh[hb + 1] = h23;
      }
    }
  }
}

// ---- host ----------------------------------------------------------------

extern "C" void kernel_launch(void* const* d_in, const int* in_sizes, int n_in,
                              void* d_out, int out_size, void* d_ws, size_t ws_size,
                              hipStream_t stream) {
  const float* x_in     = (const float*)d_in[0];
  const float* e_in     = (const float*)d_in[1];
  const int*   hei      = (const int*)d_in[2];
  const float* dist_v2e = (const float*)d_in[3];
  const float* deg_v2e  = (const float*)d_in[4];
  const float* dist_e2v = (const float*)d_in[5];
  const float* deg_e2v  = (const float*)d_in[6];
  const float* W0       = (const float*)d_in[7];
  const float* b0       = (const float*)d_in[8];
  const float* Wn       = (const float*)d_in[9];
  const float* We       = (const float*)d_in[10];
  const float* attn_w   = (const float*)d_in[11];
  const float* attn_b   = (const float*)d_in[12];
  const float* wd_w     = (const float*)d_in[13];
  const float* wd_b     = (const float*)d_in[14];
  const float* wg_w     = (const float*)d_in[15];
  const float* wg_b     = (const float*)d_in[16];

  const int N   = in_sizes[0] / DD;
  const int E   = in_sizes[1] / DD;
  const int NNZ = in_sizes[2] / 2;
  const int* nodesArr = hei;
  const int* edgesArr = hei + NNZ;

  float* out_x = (float*)d_out;
  float* out_e = (float*)d_out + (size_t)N * DD;

  // aliases inside d_out (fully overwritten by final GEMMs):
  // x-region: [Xv2h: N*256B][xh: N*256B]
  // e-region: ET interleaved table, E rows x 512B (per col-pair: {Xe1h, eh})
  __half2* Xv2h = (__half2*)out_x;
  __half2* xh   = (__half2*)((char*)out_x + (size_t)N * DD * 2);
  __half2* ET   = (__half2*)out_e;
  const float2* ETp = (const float2*)out_e;

  char* wsp = (char*)d_ws;
  auto alloc = [&](size_t bytes) -> void* {
    void* p = (void*)wsp;
    wsp += (bytes + 255) / 256 * 256;
    return p;
  };
  float* x0buf = (float*)alloc((size_t)N * DD * 4);
  float* xS1   = (float*)alloc((size_t)N * DD * 4);
  float* xS2   = (float*)alloc((size_t)N * DD * 4);
  float* eS1   = (float*)alloc((size_t)E * DD * 4);
  float* eS2   = (float*)alloc((size_t)E * DD * 4);
  float* sx1   = (float*)alloc((size_t)N * 4);
  float* sx2   = (float*)alloc((size_t)N * 4);
  float* se1   = (float*)alloc((size_t)E * 4);
  float* se2   = (float*)alloc((size_t)E * 4);
  float* a_v2e = (float*)alloc((size_t)NNZ * 4);
  float* degV  = (float*)alloc((size_t)N * 4);
  float* degE  = (float*)alloc((size_t)E * 4);
  float4* pack = (float4*)alloc((size_t)NNZ * 16);
  int* dV_i  = (int*)alloc((size_t)N * 4);
  int* no_   = (int*)alloc((size_t)(N + 1) * 4);
  int* nfill = (int*)alloc((size_t)N * 4);
  int* perm  = (int*)alloc((size_t)NNZ * 4);
  int* eo    = (int*)alloc((size_t)(E + 1) * 4);
  int* part  = (int*)alloc((size_t)SCAN_BLOCKS * 4);

  // ---- setup
  hipMemsetAsync(dV_i, 0, (size_t)N * 4, stream);
  k_edge_offsets<<<(E + 1 + 255) / 256, 256, 0, stream>>>(edgesArr, NNZ, E, eo);
  k_hist<<<(NNZ + 255) / 256, 256, 0, stream>>>(nodesArr, NNZ, dV_i);
  k_scan_partial<<<SCAN_BLOCKS, 256, 0, stream>>>(dV_i, N, part);
  k_scan_blocksums<<<1, SCAN_BLOCKS, 0, stream>>>(part);
  k_scan_apply<<<SCAN_BLOCKS, 256, 0, stream>>>(dV_i, N, NNZ, part, no_, nfill, degV);
  k_perm<<<(NNZ + 255) / 256, 256, 0, stream>>>(nodesArr, NNZ, nfill, perm);
  k_pack<<<(NNZ + 255) / 256, 256, 0, stream>>>(perm, edgesArr, dist_e2v, deg_e2v, NNZ, pack);
  k_edge_deg<<<(E + 255) / 256, 256, 0, stream>>>(nodesArr, eo, E, dV_i, degE);

  // eh (layer 0) into ET .y slots
  k_tohalf_et<<<((E * 64) + 255) / 256, 256, 0, stream>>>((const float2*)e_in, ET, E * 64);

  // x0 = relu(x @ W0 + b0), dual write xh
  dim3 g0((N + 63) / 64, 2);
  k_gemm<<<g0, 256, 0, stream>>>(x_in, W0, b0, x0buf, xh, 0, N, 0.f, 0, 1);

  const float* xcur = x0buf;
  const float* ecur = e_in;

  for (int i = 0; i < 4; i++){
    float beta = logf(0.5f / (float)(i + 1) + 1.0f);
    float* xi_t = (i == 0) ? xS1 : (float*)xcur;
    float* xnew = (i == 3) ? out_x : ((i == 0 || i == 2) ? xS2 : xS1);
    float* ei_t = (i == 0) ? eS1 : (float*)ecur;
    float* enew = (i == 3) ? out_e : ((i == 0 || i == 2) ? eS2 : eS1);

    const float* aw1 = attn_w + (size_t)i * 256;        // aw[i,:d]
    const float* aw2 = attn_w + (size_t)i * 256 + 128;  // aw[i,d:]

    k_scores<<<(N + 3) / 4, 256, 0, stream>>>(xh, N, aw1, aw2, sx1, sx2);
    k_scores_et<<<(E + 3) / 4, 256, 0, stream>>>(ETp, E, aw2, aw1, se1, se2);

    k_softmax_v2e<<<(E + 3) / 4, 256, 0, stream>>>(nodesArr, eo, sx1, se1,
        dist_v2e, deg_v2e, attn_b, wd_w, wd_b, wg_w, wg_b, i, E, a_v2e);

    k_agg1<<<(E + 3) / 4, 256, 0, stream>>>(nodesArr, eo, xh, a_v2e, degE, E, ET);
    k_agg2f<<<(N + 3) / 4, 256, 0, stream>>>(pack, no_, se2, sx2,
        attn_b, wd_w, wd_b, wg_w, wg_b, i,
        ETp, degV, x0buf, N, Xv2h, xi_t);
    k_agg3<<<(E + 3) / 4, 256, 0, stream>>>(nodesArr, eo, Xv2h, a_v2e, degE, ETp, e_in, E, ei_t);

    dim3 gx((N + 63) / 64, 2), ge((E + 63) / 64, 2);
    k_gemm<<<gx, 256, 0, stream>>>(xi_t, Wn + (size_t)i * DD * DD, nullptr, xnew,
                                   (i == 3) ? nullptr : xh, 0, N, beta, 1, i < 3 ? 1 : 0);
    k_gemm<<<ge, 256, 0, stream>>>(ei_t, We + (size_t)i * DD * DD, nullptr, enew,
                                   (i == 3) ? nullptr : ET, 1, E, beta, 1, i < 3 ? 1 : 0);

    xcur = xnew; ecur = enew;
  }
}

// Round 5
// 1116.475 us; speedup vs baseline: 1.8586x; 1.0207x over previous
//
#include <hip/hip_runtime.h>
#include <hip/hip_fp16.h>
#include <math.h>

#define DD 128
#define SCAN_BLOCKS 256

typedef _Float16 f16x8 __attribute__((ext_vector_type(8)));
typedef float f32x4 __attribute__((ext_vector_type(4)));

__device__ inline float wave_sum(float v){
#pragma unroll
  for (int m = 32; m >= 1; m >>= 1) v += __shfl_xor(v, m, 64);
  return v;
}
__device__ inline float wave_max(float v){
#pragma unroll
  for (int m = 32; m >= 1; m >>= 1) v = fmaxf(v, __shfl_xor(v, m, 64));
  return v;
}
__device__ inline int wave_sum_i(int v){
#pragma unroll
  for (int m = 32; m >= 1; m >>= 1) v += __shfl_xor(v, m, 64);
  return v;
}

// ---- setup kernels -------------------------------------------------------

__global__ void k_edge_offsets(const int* __restrict__ edges, int nnz, int E,
                               int* __restrict__ eo){
  int e = blockIdx.x * blockDim.x + threadIdx.x;
  if (e > E) return;
  int lo = 0, hi = nnz;
  while (lo < hi){ int mid = (lo + hi) >> 1; if (edges[mid] < e) lo = mid + 1; else hi = mid; }
  eo[e] = lo;
}

__global__ void k_hist(const int* __restrict__ nodes, int nnz, int* __restrict__ dV){
  int k = blockIdx.x * blockDim.x + threadIdx.x;
  if (k < nnz) atomicAdd(&dV[nodes[k]], 1);
}

__global__ __launch_bounds__(256) void k_scan_partial(const int* __restrict__ dV, int N,
                                                      int* __restrict__ part){
  int b = blockIdx.x, t = threadIdx.x;
  int chunk = (N + SCAN_BLOCKS - 1) / SCAN_BLOCKS;
  int s0 = b * chunk, s1 = min(s0 + chunk, N);
  int sum = 0;
  for (int n = s0 + t; n < s1; n += 256) sum += dV[n];
  sum = wave_sum_i(sum);
  __shared__ int wred[4];
  int lane = t & 63, wid = t >> 6;
  if (lane == 0) wred[wid] = sum;
  __syncthreads();
  if (t == 0) part[b] = wred[0] + wred[1] + wred[2] + wred[3];
}

__global__ __launch_bounds__(SCAN_BLOCKS) void k_scan_blocksums(int* __restrict__ part){
  __shared__ int sh[SCAN_BLOCKS];
  int t = threadIdx.x;
  int v = part[t];
  sh[t] = v; __syncthreads();
  for (int off = 1; off < SCAN_BLOCKS; off <<= 1){
    int add = (t >= off) ? sh[t - off] : 0;
    __syncthreads();
    sh[t] += add;
    __syncthreads();
  }
  part[t] = sh[t] - v;
}

__global__ __launch_bounds__(256) void k_scan_apply(const int* __restrict__ dV, int N, int nnz,
    const int* __restrict__ partScan, int* __restrict__ no, int* __restrict__ nfill,
    float* __restrict__ degV){
  int b = blockIdx.x, t = threadIdx.x;
  int chunk = (N + SCAN_BLOCKS - 1) / SCAN_BLOCKS;
  int s0 = b * chunk, s1 = min(s0 + chunk, N);
  int lane = t & 63, wid = t >> 6;
  __shared__ int wtot[4];
  __shared__ int s_run;
  if (t == 0) s_run = partScan[b];
  __syncthreads();
  for (int base = s0; base < s1; base += 256){
    int n = base + t;
    int d = (n < s1) ? dV[n] : 0;
    int v = d;
#pragma unroll
    for (int off = 1; off < 64; off <<= 1){
      int o = __shfl_up(v, off, 64);
      if (lane >= off) v += o;
    }
    if (lane == 63) wtot[wid] = v;
    __syncthreads();
    int run0 = s_run;
    int woff = 0;
    for (int w = 0; w < wid; w++) woff += wtot[w];
    if (n < s1){
      int excl = run0 + woff + v - d;
      no[n] = excl; nfill[n] = excl;
      degV[n] = d > 0 ? 1.0f / sqrtf((float)d) : 1.0f;
    }
    int btot = wtot[0] + wtot[1] + wtot[2] + wtot[3];
    __syncthreads();
    if (t == 0) s_run = run0 + btot;
    __syncthreads();
  }
  if (b == 0 && t == 0) no[N] = nnz;
}

__global__ void k_perm(const int* __restrict__ nodes, int nnz,
                       int* __restrict__ nfill, int* __restrict__ perm){
  int k = blockIdx.x * blockDim.x + threadIdx.x;
  if (k < nnz){ int pos = atomicAdd(&nfill[nodes[k]], 1); perm[pos] = k; }
}

// pack[j] = {edges[perm[j]] as float-bits, dist_e2v[perm[j]], deg_e2v[perm[j]], 0}
__global__ void k_pack(const int* __restrict__ perm, const int* __restrict__ edges,
                       const float* __restrict__ dist, const float* __restrict__ deg,
                       int nnz, float4* __restrict__ pack){
  int j = blockIdx.x * blockDim.x + threadIdx.x;
  if (j < nnz){
    int k = perm[j];
    pack[j] = make_float4(__int_as_float(edges[k]), dist[k], deg[k], 0.f);
  }
}

__global__ void k_edge_deg(const int* __restrict__ nodes, const int* __restrict__ eo, int E,
                           const int* __restrict__ dV, float* __restrict__ degE){
  int e = blockIdx.x * blockDim.x + threadIdx.x;
  if (e >= E) return;
  int b = eo[e], en = eo[e + 1];
  float s = 0.f;
  for (int k = b; k < en; k++) s += (float)dV[nodes[k]];
  float cnt = (float)(en - b);
  float dE = s / fmaxf(cnt, 1.0f);
  degE[e] = dE > 0.f ? 1.0f / sqrtf(dE) : 1.0f;
}

// f32 -> f16 into interleaved ET .y slots (n half2 elements)
__global__ void k_tohalf_et(const float2* __restrict__ src, __half2* __restrict__ ET, int n){
  int i = blockIdx.x * blockDim.x + threadIdx.x;
  if (i < n){ float2 v = src[i]; ET[(size_t)i * 2 + 1] = __floats2half2_rn(v.x, v.y); }
}

// f32 -> f16 linear
__global__ void k_tohalf(const float2* __restrict__ src, __half2* __restrict__ dst, int n){
  int i = blockIdx.x * blockDim.x + threadIdx.x;
  if (i < n){ float2 v = src[i]; dst[i] = __floats2half2_rn(v.x, v.y); }
}

// transpose-cast the 9 weight matrices to fp16: Wt[m][n*128+k] = W_m[k*128+n]
__global__ void k_wcast(const float* __restrict__ W0, const float* __restrict__ Wn,
                        const float* __restrict__ We, _Float16* __restrict__ Wt){
  int idx = blockIdx.x * 256 + threadIdx.x;
  if (idx >= 9 * 16384) return;
  int m = idx >> 14, r = idx & 16383;
  int n = r >> 7, k = r & 127;
  const float* src = (m == 0) ? W0 : (m <= 4 ? Wn + (size_t)(m - 1) * 16384
                                             : We + (size_t)(m - 5) * 16384);
  Wt[(size_t)m * 16384 + n * 128 + k] = (_Float16)src[k * 128 + n];
}

// ---- per-layer kernels ---------------------------------------------------

// linear fp16 rows (xh)
__global__ __launch_bounds__(256) void k_scores(const __half2* __restrict__ rows, int nrows,
                        const float* __restrict__ va, const float* __restrict__ vb,
                        float* __restrict__ outA, float* __restrict__ outB){
  int wave = threadIdx.x >> 6, lane = threadIdx.x & 63;
  int r = blockIdx.x * 4 + wave;
  if (r >= nrows) return;
  float2 x = __half22float2(rows[(size_t)r * 64 + lane]);
  float2 a = ((const float2*)va)[lane];
  float2 b = ((const float2*)vb)[lane];
  float s1 = x.x * a.x + x.y * a.y;
  float s2 = x.x * b.x + x.y * b.y;
  s1 = wave_sum(s1); s2 = wave_sum(s2);
  if (lane == 0){ outA[r] = s1; outB[r] = s2; }
}

// interleaved ET rows, use .y (= eh)
__global__ __launch_bounds__(256) void k_scores_et(const float2* __restrict__ ETp, int nrows,
                        const float* __restrict__ va, const float* __restrict__ vb,
                        float* __restrict__ outA, float* __restrict__ outB){
  int wave = threadIdx.x >> 6, lane = threadIdx.x & 63;
  int r = blockIdx.x * 4 + wave;
  if (r >= nrows) return;
  float2 q = ETp[(size_t)r * 64 + lane];
  float2 x = __half22float2(*(__half2*)&q.y);
  float2 a = ((const float2*)va)[lane];
  float2 b = ((const float2*)vb)[lane];
  float s1 = x.x * a.x + x.y * a.y;
  float s2 = x.x * b.x + x.y * b.y;
  s1 = wave_sum(s1); s2 = wave_sum(s2);
  if (lane == 0){ outA[r] = s1; outB[r] = s2; }
}

// softmax over contiguous (sorted) edge segments; wave per edge
__global__ __launch_bounds__(256) void k_softmax_v2e(
    const int* __restrict__ nodes, const int* __restrict__ eo,
    const float* __restrict__ sx1, const float* __restrict__ se1,
    const float* __restrict__ dist, const float* __restrict__ deg,
    const float* __restrict__ ab, const float* __restrict__ wdw, const float* __restrict__ wdb,
    const float* __restrict__ wgw, const float* __restrict__ wgb, int li,
    int E, float* __restrict__ a_out){
  int wave = threadIdx.x >> 6, lane = threadIdx.x & 63;
  int e = blockIdx.x * 4 + wave;
  if (e >= E) return;
  int b = eo[e], en = eo[e + 1];
  if (b >= en) return;
  float base = se1[e] + ab[li] + wdb[li] + wgb[li];
  float wd = wdw[li], wg = wgw[li];
  float m = -INFINITY;
  for (int k = b + lane; k < en; k += 64){
    float s = sx1[nodes[k]] + base + dist[k] * wd + deg[k] * wg;
    a_out[k] = s;
    m = fmaxf(m, s);
  }
  m = wave_max(m);
  float sum = 0.f;
  for (int k = b + lane; k < en; k += 64){
    float ex = expf(a_out[k] - m);
    a_out[k] = ex; sum += ex;
  }
  sum = wave_sum(sum);
  for (int k = b + lane; k < en; k += 64) a_out[k] = a_out[k] / sum;
}

// pass1: ET[e].x-slots = degE[e] * sum_k a_v2e[k]*xh[nodes[k],:]  (wave per edge, 8x unroll)
__global__ __launch_bounds__(256) void k_agg1(const int* __restrict__ nodes, const int* __restrict__ eo,
    const __half2* __restrict__ xh, const float* __restrict__ a_v2e, const float* __restrict__ degE,
    int E, __half2* __restrict__ ET){
  int wave = threadIdx.x >> 6, lane = threadIdx.x & 63;
  int e = blockIdx.x * 4 + wave;
  if (e >= E) return;
  int b = eo[e], en = eo[e + 1];
  float2 acc = make_float2(0.f, 0.f);
  int k = b;
  for (; k + 7 < en; k += 8){
    int n[8]; float w[8]; float2 v[8];
#pragma unroll
    for (int u = 0; u < 8; u++){ n[u] = nodes[k + u]; w[u] = a_v2e[k + u]; }
#pragma unroll
    for (int u = 0; u < 8; u++) v[u] = __half22float2(xh[(size_t)n[u] * 64 + lane]);
#pragma unroll
    for (int u = 0; u < 8; u++){ acc.x += w[u] * v[u].x; acc.y += w[u] * v[u].y; }
  }
  for (; k < en; k++){
    int n = nodes[k];
    float w = a_v2e[k];
    float2 v = __half22float2(xh[(size_t)n * 64 + lane]);
    acc.x += w * v.x; acc.y += w * v.y;
  }
  float dE = degE[e];
  ET[((size_t)e * 64 + lane) * 2] = __floats2half2_rn(acc.x * dE, acc.y * dE);
}

// pass2 FUSED with e2v softmax: wave per node; packed CSR payload; interleaved ET loads
__global__ __launch_bounds__(256) void k_agg2f(
    const float4* __restrict__ pack, const int* __restrict__ no,
    const float* __restrict__ se2, const float* __restrict__ sx2,
    const float* __restrict__ ab, const float* __restrict__ wdw, const float* __restrict__ wdb,
    const float* __restrict__ wgw, const float* __restrict__ wgb, int li,
    const float2* __restrict__ ETp,
    const float* __restrict__ degV, const float* __restrict__ x0,
    int N, __half2* __restrict__ Xv2h, float* __restrict__ xi, __half2* __restrict__ xiH){
  int wave = threadIdx.x >> 6, lane = threadIdx.x & 63;
  int n = blockIdx.x * 4 + wave;
  if (n >= N) return;
  int b = no[n], en = no[n + 1];
  float base = sx2[n] + ab[li] + wdb[li] + wgb[li];
  float wd = wdw[li], wg = wgw[li];
  float m_run = -INFINITY, l_run = 0.f;
  float2 a1 = make_float2(0.f, 0.f), a2 = make_float2(0.f, 0.f);
  for (int cb = b; cb < en; cb += 64){
    int cs = min(64, en - cb);
    float s = -INFINITY; int e_l = 0;
    if (lane < cs){
      float4 pk = pack[cb + lane];
      e_l = __float_as_int(pk.x);
      s = se2[e_l] + base + pk.y * wd + pk.z * wg;
    }
    float m_c = wave_max(s);
    float p = (lane < cs) ? expf(s - m_c) : 0.f;
    float l_c = wave_sum(p);
    float m_new = fmaxf(m_run, m_c);
    float f_old = expf(m_run - m_new);
    float f_c = expf(m_c - m_new);
    a1.x *= f_old; a1.y *= f_old; a2.x *= f_old; a2.y *= f_old;
    l_run = l_run * f_old + l_c * f_c;
    m_run = m_new;
    int jj = 0;
    for (; jj + 3 < cs; jj += 4){
      float w0 = __shfl(p, jj, 64) * f_c;
      float w1 = __shfl(p, jj + 1, 64) * f_c;
      float w2 = __shfl(p, jj + 2, 64) * f_c;
      float w3 = __shfl(p, jj + 3, 64) * f_c;
      int e0 = __shfl(e_l, jj, 64);
      int e1 = __shfl(e_l, jj + 1, 64);
      int e2 = __shfl(e_l, jj + 2, 64);
      int e3 = __shfl(e_l, jj + 3, 64);
      float2 q0 = ETp[(size_t)e0 * 64 + lane];
      float2 q1 = ETp[(size_t)e1 * 64 + lane];
      float2 q2 = ETp[(size_t)e2 * 64 + lane];
      float2 q3 = ETp[(size_t)e3 * 64 + lane];
      float2 x0v, e0v;
      x0v = __half22float2(*(__half2*)&q0.x); e0v = __half22float2(*(__half2*)&q0.y);
      a1.x += w0 * x0v.x; a1.y += w0 * x0v.y; a2.x += w0 * e0v.x; a2.y += w0 * e0v.y;
      x0v = __half22float2(*(__half2*)&q1.x); e0v = __half22float2(*(__half2*)&q1.y);
      a1.x += w1 * x0v.x; a1.y += w1 * x0v.y; a2.x += w1 * e0v.x; a2.y += w1 * e0v.y;
      x0v = __half22float2(*(__half2*)&q2.x); e0v = __half22float2(*(__half2*)&q2.y);
      a1.x += w2 * x0v.x; a1.y += w2 * x0v.y; a2.x += w2 * e0v.x; a2.y += w2 * e0v.y;
      x0v = __half22float2(*(__half2*)&q3.x); e0v = __half22float2(*(__half2*)&q3.y);
      a1.x += w3 * x0v.x; a1.y += w3 * x0v.y; a2.x += w3 * e0v.x; a2.y += w3 * e0v.y;
    }
    for (; jj < cs; jj++){
      float w = __shfl(p, jj, 64) * f_c;
      int e = __shfl(e_l, jj, 64);
      float2 q = ETp[(size_t)e * 64 + lane];
      float2 v1 = __half22float2(*(__half2*)&q.x);
      float2 v2 = __half22float2(*(__half2*)&q.y);
      a1.x += w * v1.x; a1.y += w * v1.y;
      a2.x += w * v2.x; a2.y += w * v2.y;
    }
  }
  float inv = l_run > 0.f ? 1.0f / l_run : 0.f;
  float dv = degV[n] * inv;
  float2 xv1 = make_float2(a1.x * dv, a1.y * dv);
  float2 xv2 = make_float2(a2.x * dv, a2.y * dv);
  Xv2h[(size_t)n * 64 + lane] = __floats2half2_rn(xv2.x, xv2.y);
  float2 x0v = *((const float2*)(x0 + (size_t)n * DD) + lane);
  float2 o = make_float2(0.45f * (xv1.x + xv2.x) + 0.1f * x0v.x,
                         0.45f * (xv1.y + xv2.y) + 0.1f * x0v.y);
  *((float2*)(xi + (size_t)n * DD) + lane) = o;
  xiH[(size_t)n * 64 + lane] = __floats2half2_rn(o.x, o.y);
}

// pass3: per edge: Xe2 = degE*sum a_v2e*Xv2[node]; ei = 0.45*(Xe1+Xe2)+0.1*e0  (8x unroll)
__global__ __launch_bounds__(256) void k_agg3(const int* __restrict__ nodes, const int* __restrict__ eo,
    const __half2* __restrict__ Xv2h, const float* __restrict__ a_v2e, const float* __restrict__ degE,
    const float2* __restrict__ ETp, const float* __restrict__ e0,
    int E, float* __restrict__ ei, __half2* __restrict__ eiH){
  int wave = threadIdx.x >> 6, lane = threadIdx.x & 63;
  int e = blockIdx.x * 4 + wave;
  if (e >= E) return;
  int b = eo[e], en = eo[e + 1];
  float2 acc = make_float2(0.f, 0.f);
  int k = b;
  for (; k + 7 < en; k += 8){
    int n[8]; float w[8]; float2 v[8];
#pragma unroll
    for (int u = 0; u < 8; u++){ n[u] = nodes[k + u]; w[u] = a_v2e[k + u]; }
#pragma unroll
    for (int u = 0; u < 8; u++) v[u] = __half22float2(Xv2h[(size_t)n[u] * 64 + lane]);
#pragma unroll
    for (int u = 0; u < 8; u++){ acc.x += w[u] * v[u].x; acc.y += w[u] * v[u].y; }
  }
  for (; k < en; k++){
    int n = nodes[k];
    float w = a_v2e[k];
    float2 v = __half22float2(Xv2h[(size_t)n * 64 + lane]);
    acc.x += w * v.x; acc.y += w * v.y;
  }
  float dE = degE[e];
  float2 q = ETp[(size_t)e * 64 + lane];
  float2 xe1 = __half22float2(*(__half2*)&q.x);
  float2 e0v = *((const float2*)(e0 + (size_t)e * DD) + lane);
  float2 o = make_float2(0.45f * (xe1.x + acc.x * dE) + 0.1f * e0v.x,
                         0.45f * (xe1.y + acc.y * dE) + 0.1f * e0v.y);
  *((float2*)(ei + (size_t)e * DD) + lane) = o;
  eiH[(size_t)e * 64 + lane] = __floats2half2_rn(o.x, o.y);
}

// MFMA GEMM: 256 thr / 4 waves, 64 rows x 128 cols per block, K=128.
// Ah: fp16 row-major A. Wt: fp16 W transposed [n][k].
// mode 0: relu(acc + bias[c]); mode 1: (1-beta)*Af[r,c] + beta*acc (+relu)
// outf (f32) and outh (fp16; et=0 linear, et=1 ET .y slots) each optional.
__global__ __launch_bounds__(256) void k_gemm_mfma(
    const _Float16* __restrict__ Ah, const _Float16* __restrict__ Wt,
    const float* __restrict__ Af, const float* __restrict__ bias,
    float* __restrict__ outf, _Float16* __restrict__ outh, int et,
    int nrows, float beta, int mode, int do_relu){
  int wave = threadIdx.x >> 6, lane = threadIdx.x & 63;
  int row0 = blockIdx.x * 64 + wave * 16;
  if (row0 >= nrows) return;
  int lm = lane & 15;
  int lk8 = (lane >> 4) * 8;
  int arow = row0 + lm; if (arow >= nrows) arow = nrows - 1;
  f16x8 afrag[4];
#pragma unroll
  for (int ks = 0; ks < 4; ks++)
    afrag[ks] = *(const f16x8*)(Ah + (size_t)arow * 128 + ks * 32 + lk8);
  int rbase = (lane >> 4) * 4;
  for (int t = 0; t < 8; t++){
    f32x4 acc = {0.f, 0.f, 0.f, 0.f};
#pragma unroll
    for (int ks = 0; ks < 4; ks++){
      f16x8 bf = *(const f16x8*)(Wt + (size_t)(t * 16 + lm) * 128 + ks * 32 + lk8);
      acc = __builtin_amdgcn_mfma_f32_16x16x32_f16(afrag[ks], bf, acc, 0, 0, 0);
    }
    int col = t * 16 + lm;
#pragma unroll
    for (int r = 0; r < 4; r++){
      int gr = row0 + rbase + r;
      if (gr >= nrows) continue;
      float v;
      if (mode == 0) v = acc[r] + bias[col];
      else v = (1.0f - beta) * Af[(size_t)gr * 128 + col] + beta * acc[r];
      if (do_relu) v = fmaxf(v, 0.f);
      if (outf) outf[(size_t)gr * 128 + col] = v;
      if (outh){
        if (et) outh[(size_t)gr * 256 + (col >> 1) * 4 + 2 + (col & 1)] = (_Float16)v;
        else    outh[(size_t)gr * 128 + col] = (_Float16)v;
      }
    }
  }
}

// ---- host ----------------------------------------------------------------

extern "C" void kernel_launch(void* const* d_in, const int* in_sizes, int n_in,
                              void* d_out, int out_size, void* d_ws, size_t ws_size,
                              hipStream_t stream) {
  const float* x_in     = (const float*)d_in[0];
  const float* e_in     = (const float*)d_in[1];
  const int*   hei      = (const int*)d_in[2];
  const float* dist_v2e = (const float*)d_in[3];
  const float* deg_v2e  = (const float*)d_in[4];
  const float* dist_e2v = (const float*)d_in[5];
  const float* deg_e2v  = (const float*)d_in[6];
  const float* W0       = (const float*)d_in[7];
  const float* b0       = (const float*)d_in[8];
  const float* Wn       = (const float*)d_in[9];
  const float* We       = (const float*)d_in[10];
  const float* attn_w   = (const float*)d_in[11];
  const float* attn_b   = (const float*)d_in[12];
  const float* wd_w     = (const float*)d_in[13];
  const float* wd_b     = (const float*)d_in[14];
  const float* wg_w     = (const float*)d_in[15];
  const float* wg_b     = (const float*)d_in[16];

  const int N   = in_sizes[0] / DD;
  const int E   = in_sizes[1] / DD;
  const int NNZ = in_sizes[2] / 2;
  const int* nodesArr = hei;
  const int* edgesArr = hei + NNZ;

  float* out_x = (float*)d_out;
  float* out_e = (float*)d_out + (size_t)N * DD;

  // aliases inside d_out (fully overwritten by final GEMMs):
  // x-region: [Xv2h: N*256B][xh: N*256B]
  // e-region: ET interleaved table, E rows x 512B (per col-pair: {Xe1h, eh})
  __half2* Xv2h = (__half2*)out_x;
  __half2* xh   = (__half2*)((char*)out_x + (size_t)N * DD * 2);
  __half2* ET   = (__half2*)out_e;
  const float2* ETp = (const float2*)out_e;

  char* wsp = (char*)d_ws;
  auto alloc = [&](size_t bytes) -> void* {
    void* p = (void*)wsp;
    wsp += (bytes + 255) / 256 * 256;
    return p;
  };
  float* x0buf = (float*)alloc((size_t)N * DD * 4);
  float* xS1   = (float*)alloc((size_t)N * DD * 4);   // xi f32 scratch
  float* eS1   = (float*)alloc((size_t)E * DD * 4);   // ei f32 scratch
  _Float16* xinh = (_Float16*)alloc((size_t)N * DD * 2);
  _Float16* xiH  = (_Float16*)alloc((size_t)N * DD * 2);
  _Float16* eiH  = (_Float16*)alloc((size_t)E * DD * 2);
  _Float16* Wt   = (_Float16*)alloc((size_t)9 * 16384 * 2);
  float* sx1   = (float*)alloc((size_t)N * 4);
  float* sx2   = (float*)alloc((size_t)N * 4);
  float* se1   = (float*)alloc((size_t)E * 4);
  float* se2   = (float*)alloc((size_t)E * 4);
  float* a_v2e = (float*)alloc((size_t)NNZ * 4);
  float* degV  = (float*)alloc((size_t)N * 4);
  float* degE  = (float*)alloc((size_t)E * 4);
  float4* pack = (float4*)alloc((size_t)NNZ * 16);
  int* dV_i  = (int*)alloc((size_t)N * 4);
  int* no_   = (int*)alloc((size_t)(N + 1) * 4);
  int* nfill = (int*)alloc((size_t)N * 4);
  int* perm  = (int*)alloc((size_t)NNZ * 4);
  int* eo    = (int*)alloc((size_t)(E + 1) * 4);
  int* part  = (int*)alloc((size_t)SCAN_BLOCKS * 4);

  // ---- setup
  hipMemsetAsync(dV_i, 0, (size_t)N * 4, stream);
  k_edge_offsets<<<(E + 1 + 255) / 256, 256, 0, stream>>>(edgesArr, NNZ, E, eo);
  k_hist<<<(NNZ + 255) / 256, 256, 0, stream>>>(nodesArr, NNZ, dV_i);
  k_scan_partial<<<SCAN_BLOCKS, 256, 0, stream>>>(dV_i, N, part);
  k_scan_blocksums<<<1, SCAN_BLOCKS, 0, stream>>>(part);
  k_scan_apply<<<SCAN_BLOCKS, 256, 0, stream>>>(dV_i, N, NNZ, part, no_, nfill, degV);
  k_perm<<<(NNZ + 255) / 256, 256, 0, stream>>>(nodesArr, NNZ, nfill, perm);
  k_pack<<<(NNZ + 255) / 256, 256, 0, stream>>>(perm, edgesArr, dist_e2v, deg_e2v, NNZ, pack);
  k_edge_deg<<<(E + 255) / 256, 256, 0, stream>>>(nodesArr, eo, E, dV_i, degE);
  k_wcast<<<(9 * 16384 + 255) / 256, 256, 0, stream>>>(W0, Wn, We, Wt);

  // eh (layer 0) into ET .y slots; x_in -> fp16
  k_tohalf_et<<<((E * 64) + 255) / 256, 256, 0, stream>>>((const float2*)e_in, ET, E * 64);
  k_tohalf<<<((N * 64) + 255) / 256, 256, 0, stream>>>((const float2*)x_in, (__half2*)xinh, N * 64);

  // x0 = relu(x @ W0 + b0): f32 -> x0buf, fp16 -> xh
  k_gemm_mfma<<<(N + 63) / 64, 256, 0, stream>>>(xinh, Wt, nullptr, b0,
      x0buf, (_Float16*)xh, 0, N, 0.f, 0, 1);

  for (int i = 0; i < 4; i++){
    float beta = logf(0.5f / (float)(i + 1) + 1.0f);
    const float* aw1 = attn_w + (size_t)i * 256;        // aw[i,:d]
    const float* aw2 = attn_w + (size_t)i * 256 + 128;  // aw[i,d:]

    k_scores<<<(N + 3) / 4, 256, 0, stream>>>(xh, N, aw1, aw2, sx1, sx2);
    k_scores_et<<<(E + 3) / 4, 256, 0, stream>>>(ETp, E, aw2, aw1, se1, se2);

    k_softmax_v2e<<<(E + 3) / 4, 256, 0, stream>>>(nodesArr, eo, sx1, se1,
        dist_v2e, deg_v2e, attn_b, wd_w, wd_b, wg_w, wg_b, i, E, a_v2e);

    k_agg1<<<(E + 3) / 4, 256, 0, stream>>>(nodesArr, eo, xh, a_v2e, degE, E, ET);
    k_agg2f<<<(N + 3) / 4, 256, 0, stream>>>(pack, no_, se2, sx2,
        attn_b, wd_w, wd_b, wg_w, wg_b, i,
        ETp, degV, x0buf, N, Xv2h, xS1, (__half2*)xiH);
    k_agg3<<<(E + 3) / 4, 256, 0, stream>>>(nodesArr, eo, Xv2h, a_v2e, degE, ETp, e_in,
                                            E, eS1, (__half2*)eiH);

    // x-GEMM: f32 out only at i=3; fp16 xh for i<3
    k_gemm_mfma<<<(N + 63) / 64, 256, 0, stream>>>(xiH, Wt + (size_t)(1 + i) * 16384,
        xS1, nullptr, (i == 3) ? out_x : nullptr, (i < 3) ? (_Float16*)xh : nullptr,
        0, N, beta, 1, i < 3 ? 1 : 0);
    // e-GEMM: f32 out only at i=3; fp16 into ET .y slots for i<3
    k_gemm_mfma<<<(E + 63) / 64, 256, 0, stream>>>(eiH, Wt + (size_t)(5 + i) * 16384,
        eS1, nullptr, (i == 3) ? out_e : nullptr, (i < 3) ? (_Float16*)ET : nullptr,
        1, E, beta, 1, i < 3 ? 1 : 0);
  }
}